// Round 1
// baseline (8154.923 us; speedup 1.0000x reference)
//
#include <hip/hip_runtime.h>

#define NN 50000          // nodes
#define D0 300
#define D1 400
#define D2 512

// ---------------- degree kernels ----------------
__global__ __launch_bounds__(256) void deg_kernel(const int* __restrict__ src,
                                                  const int* __restrict__ dst,
                                                  float* __restrict__ deg_s,
                                                  float* __restrict__ deg_d, int E) {
    int e = blockIdx.x * 256 + threadIdx.x;
    if (e < E) {
        unsafeAtomicAdd(&deg_s[src[e]], 1.0f);
        unsafeAtomicAdd(&deg_d[dst[e]], 1.0f);
    }
}

__global__ __launch_bounds__(256) void rsqrt_kernel(float* __restrict__ deg_s,
                                                    float* __restrict__ deg_d, int n) {
    int i = blockIdx.x * 256 + threadIdx.x;
    if (i < n) {
        deg_s[i] = rsqrtf(fmaxf(deg_s[i], 1.0f));
        deg_d[i] = rsqrtf(fmaxf(deg_d[i], 1.0f));
    }
}

// ---------------- edge aggregation: out[dst] += X[src] * (sscale?sscale[src]:1) ----------------
template <int D, int D4, bool SCALE>
__global__ __launch_bounds__(256) void agg_kernel(const float* __restrict__ X,
                                                  const int* __restrict__ src,
                                                  const int* __restrict__ dst,
                                                  const float* __restrict__ sscale,
                                                  float* __restrict__ out, int E) {
    unsigned tid = blockIdx.x * 256u + threadIdx.x;
    unsigned total = (unsigned)E * (unsigned)D4;
    if (tid >= total) return;
    int e = tid / D4;
    int c = (tid - e * D4) * 4;
    int s = src[e];
    int d = dst[e];
    float4 v = *(const float4*)&X[(long)s * D + c];
    if (SCALE) {
        float sc = sscale[s];
        v.x *= sc; v.y *= sc; v.z *= sc; v.w *= sc;
    }
    float* o = &out[(long)d * D + c];
    unsafeAtomicAdd(o + 0, v.x);
    unsafeAtomicAdd(o + 1, v.y);
    unsafeAtomicAdd(o + 2, v.z);
    unsafeAtomicAdd(o + 3, v.w);
}

// ---------------- f32 GEMM: C = epi( (diag(rs) * A) @ B + bias ) ----------------
// A: MxK row-major, B: KxN row-major. BM=128, BN=64, BK=16. 256 threads, 8x4 per thread.
template <bool LRELU, bool EPI_SCALE>
__global__ __launch_bounds__(256) void gemm_kernel(const float* __restrict__ A,
                                                   const float* __restrict__ B,
                                                   const float* __restrict__ bias,
                                                   const float* __restrict__ rowscale,
                                                   const float* __restrict__ episcale,
                                                   float* __restrict__ C,
                                                   int M, int N, int K) {
    const int BM = 128, BN = 64, BK = 16;
    __shared__ float As[BK][BM + 4];
    __shared__ float Bs[BK][BN + 4];
    int tid = threadIdx.x;
    int tx = tid & 15;   // col group (4 cols)
    int ty = tid >> 4;   // row group (8 rows)
    int m0 = blockIdx.x * BM;
    int n0 = blockIdx.y * BN;

    float acc[8][4] = {};

    int a_row = tid >> 2;            // 0..63, two rows per thread (+64)
    int a_kc  = (tid & 3) * 4;       // k chunk within tile (0,4,8,12)
    int b_r   = tid >> 4;            // 0..15
    int b_nq  = (tid & 15) * 4;      // col chunk

    for (int k0 = 0; k0 < K; k0 += BK) {
#pragma unroll
        for (int h = 0; h < 2; ++h) {
            int row = a_row + h * 64;
            int gm = m0 + row;
            float4 v = {0.f, 0.f, 0.f, 0.f};
            if (gm < M && (k0 + a_kc) < K) {   // K%4==0 -> whole float4 in/out
                v = *(const float4*)&A[(long)gm * K + k0 + a_kc];
                float s = rowscale[gm];
                v.x *= s; v.y *= s; v.z *= s; v.w *= s;
            }
            As[a_kc + 0][row] = v.x;
            As[a_kc + 1][row] = v.y;
            As[a_kc + 2][row] = v.z;
            As[a_kc + 3][row] = v.w;
        }
        {
            float4 v = {0.f, 0.f, 0.f, 0.f};
            int gk = k0 + b_r;
            if (gk < K && (n0 + b_nq) < N)     // N%4==0 -> whole float4 in/out
                v = *(const float4*)&B[(long)gk * N + n0 + b_nq];
            *(float4*)&Bs[b_r][b_nq] = v;
        }
        __syncthreads();
#pragma unroll
        for (int kk = 0; kk < BK; ++kk) {
            float a[8], b[4];
#pragma unroll
            for (int i = 0; i < 8; ++i) a[i] = As[kk][ty * 8 + i];
#pragma unroll
            for (int j = 0; j < 4; ++j) b[j] = Bs[kk][tx * 4 + j];
#pragma unroll
            for (int i = 0; i < 8; ++i)
#pragma unroll
                for (int j = 0; j < 4; ++j)
                    acc[i][j] += a[i] * b[j];
        }
        __syncthreads();
    }

#pragma unroll
    for (int i = 0; i < 8; ++i) {
        int gm = m0 + ty * 8 + i;
        if (gm >= M) continue;
        float es = EPI_SCALE ? episcale[gm] : 1.0f;
#pragma unroll
        for (int j = 0; j < 4; ++j) {
            int gn = n0 + tx * 4 + j;
            if (gn >= N) continue;
            float v = acc[i][j] + bias[gn];
            if (LRELU) v = v >= 0.f ? v : 0.2f * v;
            if (EPI_SCALE) v *= es;
            C[(long)gm * N + gn] = v;
        }
    }
}

extern "C" void kernel_launch(void* const* d_in, const int* in_sizes, int n_in,
                              void* d_out, int out_size, void* d_ws, size_t ws_size,
                              hipStream_t stream) {
    const float* emb = (const float*)d_in[0];
    const float* W1  = (const float*)d_in[1];
    const float* b1  = (const float*)d_in[2];
    const float* W2  = (const float*)d_in[3];
    const float* b2  = (const float*)d_in[4];
    const int*   src = (const int*)d_in[5];
    const int*   dst = (const int*)d_in[6];
    const int E = in_sizes[5];

    // ws layout: R1 (agg1 60MB / agg2 80MB) | deg_s | deg_d
    const size_t R1_BYTES = (size_t)NN * D1 * sizeof(float); // 80,000,000
    float* R1    = (float*)d_ws;
    float* deg_s = (float*)((char*)d_ws + R1_BYTES);
    float* deg_d = deg_s + NN;
    float* out   = (float*)d_out;
    float* h2    = out;   // reuse d_out (102.4MB) as h2 scratch (80MB)

    hipMemsetAsync(d_ws, 0, R1_BYTES + 2 * NN * sizeof(float), stream);

    deg_kernel<<<(E + 255) / 256, 256, 0, stream>>>(src, dst, deg_s, deg_d, E);
    rsqrt_kernel<<<(NN + 255) / 256, 256, 0, stream>>>(deg_s, deg_d, NN);

    // layer 1 aggregation in D=300: agg1[dst] += emb[src] * out_s[src]
    {
        long total = (long)E * (D0 / 4);
        agg_kernel<D0, D0 / 4, true><<<(total + 255) / 256, 256, 0, stream>>>(
            emb, src, dst, deg_s, R1, E);
    }
    // h2 = lrelu((diag(in_s) agg1) @ W1 + b1) * out_s
    gemm_kernel<true, true><<<dim3((NN + 127) / 128, (D1 + 63) / 64), 256, 0, stream>>>(
        R1, W1, b1, deg_d, deg_s, h2, NN, D1, D0);

    hipMemsetAsync(R1, 0, R1_BYTES, stream);

    // layer 2 aggregation in D=400: agg2[dst] += h2[src]
    {
        long total = (long)E * (D1 / 4);
        agg_kernel<D1, D1 / 4, false><<<(total + 255) / 256, 256, 0, stream>>>(
            h2, src, dst, nullptr, R1, E);
    }
    // out = (diag(in_s) agg2) @ W2 + b2
    gemm_kernel<false, false><<<dim3((NN + 127) / 128, (D2 + 63) / 64), 256, 0, stream>>>(
        R1, W2, b2, deg_d, nullptr, out, NN, D2, D1);
}

// Round 3
// 1025.142 us; speedup vs baseline: 7.9549x; 7.9549x over previous
//
#include <hip/hip_runtime.h>

#define NN 50000          // nodes
#define D0 300
#define D1 400
#define D2 512

// ---------------- histogram: counts of src (out-degree) and dst (in-degree) ----------------
__global__ __launch_bounds__(256) void hist_kernel(const int* __restrict__ src,
                                                   const int* __restrict__ dst,
                                                   int* __restrict__ cnt_s,
                                                   int* __restrict__ cnt_d, int E) {
    int e = blockIdx.x * 256 + threadIdx.x;
    if (e < E) {
        atomicAdd(&cnt_s[src[e]], 1);
        atomicAdd(&cnt_d[dst[e]], 1);
    }
}

// ---------------- exclusive scan of cnt (NN elems) -> offs[NN+1], single block ----------------
__global__ __launch_bounds__(1024) void scan_kernel(const int* __restrict__ cnt,
                                                    int* __restrict__ offs) {
    __shared__ int sums[1024];
    const int PER = (NN + 1023) / 1024;   // 49
    int tid = threadIdx.x;
    int base = tid * PER;
    int s = 0;
    for (int i = 0; i < PER; ++i) {
        int idx = base + i;
        if (idx < NN) s += cnt[idx];
    }
    sums[tid] = s;
    __syncthreads();
    for (int off = 1; off < 1024; off <<= 1) {
        int v = (tid >= off) ? sums[tid - off] : 0;
        __syncthreads();
        sums[tid] += v;
        __syncthreads();
    }
    int run = (tid > 0) ? sums[tid - 1] : 0;
    for (int i = 0; i < PER; ++i) {
        int idx = base + i;
        if (idx < NN) { offs[idx] = run; run += cnt[idx]; }
    }
    if (tid == 1023) offs[NN] = sums[1023];
}

// ---------------- degrees -> rsqrt scales ----------------
__global__ __launch_bounds__(256) void rsqrt_kernel(const int* __restrict__ cnt_s,
                                                    const int* __restrict__ cnt_d,
                                                    float* __restrict__ deg_s,
                                                    float* __restrict__ deg_d, int n) {
    int i = blockIdx.x * 256 + threadIdx.x;
    if (i < n) {
        deg_s[i] = rsqrtf(fmaxf((float)cnt_s[i], 1.0f));
        deg_d[i] = rsqrtf(fmaxf((float)cnt_d[i], 1.0f));
    }
}

// ---------------- scatter edges into CSR-by-dst: ssrc[offs[d] + pos] = src ----------------
__global__ __launch_bounds__(256) void scatter_kernel(const int* __restrict__ src,
                                                      const int* __restrict__ dst,
                                                      const int* __restrict__ offs,
                                                      int* __restrict__ cursor,
                                                      int* __restrict__ ssrc, int E) {
    int e = blockIdx.x * 256 + threadIdx.x;
    if (e < E) {
        int d = dst[e];
        int pos = atomicAdd(&cursor[d], 1);
        ssrc[offs[d] + pos] = src[e];
    }
}

// ---------------- CSR aggregation: out[n] = sum_{s in N_in(n)} X[s] * (sscale?sscale[s]:1) ----
// One 64-lane wave per node; lane l owns float4 chunks l and l+64.
template <int D, bool SCALE>
__global__ __launch_bounds__(256) void agg_csr_kernel(const float* __restrict__ X,
                                                      const int* __restrict__ offs,
                                                      const int* __restrict__ ssrc,
                                                      const float* __restrict__ sscale,
                                                      float* __restrict__ out) {
    constexpr int C = D / 4;              // 75 or 100 float4 chunks per row
    int node = blockIdx.x * 4 + (threadIdx.x >> 6);
    if (node >= NN) return;
    int lane = threadIdx.x & 63;
    int start = offs[node], end = offs[node + 1];
    bool has2 = (lane + 64) < C;

    float4 acc0 = {0.f, 0.f, 0.f, 0.f};
    float4 acc1 = {0.f, 0.f, 0.f, 0.f};
    for (int j = start; j < end; ++j) {
        int s = ssrc[j];                           // wave-uniform load
        const float4* row = (const float4*)&X[(long)s * D];
        float sc = SCALE ? sscale[s] : 1.0f;       // wave-uniform
        float4 v = row[lane];
        acc0.x += v.x * sc; acc0.y += v.y * sc; acc0.z += v.z * sc; acc0.w += v.w * sc;
        if (has2) {
            float4 w = row[lane + 64];
            acc1.x += w.x * sc; acc1.y += w.y * sc; acc1.z += w.z * sc; acc1.w += w.w * sc;
        }
    }
    float4* o = (float4*)&out[(long)node * D];
    o[lane] = acc0;
    if (has2) o[lane + 64] = acc1;
}

// ---------------- f32 GEMM: C = epi( (diag(rs) * A) @ B + bias ) ----------------
// A: MxK row-major, B: KxN row-major. BM=128, BN=64, BK=16. 256 threads, 8x4 per thread.
template <bool LRELU, bool EPI_SCALE>
__global__ __launch_bounds__(256) void gemm_kernel(const float* __restrict__ A,
                                                   const float* __restrict__ B,
                                                   const float* __restrict__ bias,
                                                   const float* __restrict__ rowscale,
                                                   const float* __restrict__ episcale,
                                                   float* __restrict__ C,
                                                   int M, int N, int K) {
    const int BM = 128, BN = 64, BK = 16;
    __shared__ float As[BK][BM + 4];
    __shared__ float Bs[BK][BN + 4];
    int tid = threadIdx.x;
    int tx = tid & 15;   // col group (4 cols)
    int ty = tid >> 4;   // row group (8 rows)
    int m0 = blockIdx.x * BM;
    int n0 = blockIdx.y * BN;

    float acc[8][4] = {};

    int a_row = tid >> 2;            // 0..63, two rows per thread (+64)
    int a_kc  = (tid & 3) * 4;       // k chunk within tile (0,4,8,12)
    int b_r   = tid >> 4;            // 0..15
    int b_nq  = (tid & 15) * 4;      // col chunk

    for (int k0 = 0; k0 < K; k0 += BK) {
#pragma unroll
        for (int h = 0; h < 2; ++h) {
            int row = a_row + h * 64;
            int gm = m0 + row;
            float4 v = {0.f, 0.f, 0.f, 0.f};
            if (gm < M && (k0 + a_kc) < K) {   // K%4==0 -> whole float4 in/out
                v = *(const float4*)&A[(long)gm * K + k0 + a_kc];
                float s = rowscale[gm];
                v.x *= s; v.y *= s; v.z *= s; v.w *= s;
            }
            As[a_kc + 0][row] = v.x;
            As[a_kc + 1][row] = v.y;
            As[a_kc + 2][row] = v.z;
            As[a_kc + 3][row] = v.w;
        }
        {
            float4 v = {0.f, 0.f, 0.f, 0.f};
            int gk = k0 + b_r;
            if (gk < K && (n0 + b_nq) < N)     // N%4==0 -> whole float4 in/out
                v = *(const float4*)&B[(long)gk * N + n0 + b_nq];
            *(float4*)&Bs[b_r][b_nq] = v;
        }
        __syncthreads();
#pragma unroll
        for (int kk = 0; kk < BK; ++kk) {
            float a[8], b[4];
#pragma unroll
            for (int i = 0; i < 8; ++i) a[i] = As[kk][ty * 8 + i];
#pragma unroll
            for (int j = 0; j < 4; ++j) b[j] = Bs[kk][tx * 4 + j];
#pragma unroll
            for (int i = 0; i < 8; ++i)
#pragma unroll
                for (int j = 0; j < 4; ++j)
                    acc[i][j] += a[i] * b[j];
        }
        __syncthreads();
    }

#pragma unroll
    for (int i = 0; i < 8; ++i) {
        int gm = m0 + ty * 8 + i;
        if (gm >= M) continue;
        float es = EPI_SCALE ? episcale[gm] : 1.0f;
#pragma unroll
        for (int j = 0; j < 4; ++j) {
            int gn = n0 + tx * 4 + j;
            if (gn >= N) continue;
            float v = acc[i][j] + bias[gn];
            if (LRELU) v = v >= 0.f ? v : 0.2f * v;
            if (EPI_SCALE) v *= es;
            C[(long)gm * N + gn] = v;
        }
    }
}

extern "C" void kernel_launch(void* const* d_in, const int* in_sizes, int n_in,
                              void* d_out, int out_size, void* d_ws, size_t ws_size,
                              hipStream_t stream) {
    const float* emb = (const float*)d_in[0];
    const float* W1  = (const float*)d_in[1];
    const float* b1  = (const float*)d_in[2];
    const float* W2  = (const float*)d_in[3];
    const float* b2  = (const float*)d_in[4];
    const int*   src = (const int*)d_in[5];
    const int*   dst = (const int*)d_in[6];
    const int E = in_sizes[5];

    // ws layout: R1 (agg output, 80MB) | deg_s | deg_d   (deg_d is read by the
    // final GEMM while it writes d_out, so scales must NOT live in d_out)
    const size_t R1_BYTES = (size_t)NN * D1 * sizeof(float); // 80,000,000
    float* R1    = (float*)d_ws;
    float* deg_s = (float*)((char*)d_ws + R1_BYTES);
    float* deg_d = deg_s + NN;

    float* out = (float*)d_out;
    float* h2  = out;                                  // d_out[0 .. 80MB) as h2 scratch
    // CSR scratch in the dead tail of d_out (h2 uses 80MB of 102.4MB); all CSR
    // data is dead before the final GEMM overwrites d_out.
    char*  tail   = (char*)d_out + R1_BYTES;
    int*   cnt_s  = (int*)tail;                        // NN
    int*   cnt_d  = cnt_s + NN;                        // NN
    int*   offs   = cnt_d + NN;                        // NN+1
    int*   cursor = offs + NN + 1;                     // NN
    int*   ssrc   = cursor + NN;                       // E
    // total CSR ints: 4*NN+1 + E = 1,000,001 -> 4MB, fits in 22.4MB tail

    // zero counts + offs + CURSOR (must include cursor: it is atomicAdd'd!)
    hipMemsetAsync(cnt_s, 0, (size_t)(4 * NN + 1) * sizeof(int), stream);

    hist_kernel<<<(E + 255) / 256, 256, 0, stream>>>(src, dst, cnt_s, cnt_d, E);
    scan_kernel<<<1, 1024, 0, stream>>>(cnt_d, offs);
    rsqrt_kernel<<<(NN + 255) / 256, 256, 0, stream>>>(cnt_s, cnt_d, deg_s, deg_d, NN);
    scatter_kernel<<<(E + 255) / 256, 256, 0, stream>>>(src, dst, offs, cursor, ssrc, E);

    // layer 1 aggregation in D=300: agg1[n] = sum emb[s] * out_s[s]
    agg_csr_kernel<D0, true><<<(NN + 3) / 4, 256, 0, stream>>>(emb, offs, ssrc, deg_s, R1);

    // h2 = lrelu((diag(in_s) agg1) @ W1 + b1) * out_s
    gemm_kernel<true, true><<<dim3((NN + 127) / 128, (D1 + 63) / 64), 256, 0, stream>>>(
        R1, W1, b1, deg_d, deg_s, h2, NN, D1, D0);

    // layer 2 aggregation in D=400: agg2[n] = sum h2[s]
    agg_csr_kernel<D1, false><<<(NN + 3) / 4, 256, 0, stream>>>(h2, offs, ssrc, nullptr, R1);

    // out = (diag(in_s) agg2) @ W2 + b2
    gemm_kernel<false, false><<<dim3((NN + 127) / 128, (D2 + 63) / 64), 256, 0, stream>>>(
        R1, W2, b2, deg_d, nullptr, out, NN, D2, D1);
}

// Round 4
// 709.440 us; speedup vs baseline: 11.4949x; 1.4450x over previous
//
#include <hip/hip_runtime.h>

#define NN   50000      // nodes
#define NNP  50048      // padded to 128-multiple (391 * 128)
#define D0   300        // emb dim
#define K1   320        // D0 padded to 64-multiple
#define N1   400        // layer-1 out dim
#define N1P  448        // N1 padded to 64-multiple (also GEMM2's Kpad)
#define K2   448        // N1 padded (= GEMM2 K)
#define N2   512        // layer-2 out dim

typedef __attribute__((ext_vector_type(8))) short bf16x8;
typedef __attribute__((ext_vector_type(4))) float f32x4;

__device__ __forceinline__ unsigned short f2bf(float x) {   // rn-even f32->bf16
    union { float f; unsigned u; } v; v.f = x;
    unsigned r = v.u + 0x7fffu + ((v.u >> 16) & 1u);
    return (unsigned short)(r >> 16);
}
__device__ __forceinline__ float bf2f(unsigned short h) {
    union { unsigned u; float f; } v; v.u = ((unsigned)h) << 16;
    return v.f;
}

// ---------------- CSR build (unchanged from R3) ----------------
__global__ __launch_bounds__(256) void hist_kernel(const int* __restrict__ src,
                                                   const int* __restrict__ dst,
                                                   int* __restrict__ cnt_s,
                                                   int* __restrict__ cnt_d, int E) {
    int e = blockIdx.x * 256 + threadIdx.x;
    if (e < E) {
        atomicAdd(&cnt_s[src[e]], 1);
        atomicAdd(&cnt_d[dst[e]], 1);
    }
}

__global__ __launch_bounds__(1024) void scan_kernel(const int* __restrict__ cnt,
                                                    int* __restrict__ offs) {
    __shared__ int sums[1024];
    const int PER = (NN + 1023) / 1024;
    int tid = threadIdx.x;
    int base = tid * PER;
    int s = 0;
    for (int i = 0; i < PER; ++i) {
        int idx = base + i;
        if (idx < NN) s += cnt[idx];
    }
    sums[tid] = s;
    __syncthreads();
    for (int off = 1; off < 1024; off <<= 1) {
        int v = (tid >= off) ? sums[tid - off] : 0;
        __syncthreads();
        sums[tid] += v;
        __syncthreads();
    }
    int run = (tid > 0) ? sums[tid - 1] : 0;
    for (int i = 0; i < PER; ++i) {
        int idx = base + i;
        if (idx < NN) { offs[idx] = run; run += cnt[idx]; }
    }
    if (tid == 1023) offs[NN] = sums[1023];
}

__global__ __launch_bounds__(256) void rsqrt_kernel(const int* __restrict__ cnt_s,
                                                    const int* __restrict__ cnt_d,
                                                    float* __restrict__ deg_s,
                                                    float* __restrict__ deg_d, int n) {
    int i = blockIdx.x * 256 + threadIdx.x;
    if (i < n) {
        deg_s[i] = rsqrtf(fmaxf((float)cnt_s[i], 1.0f));
        deg_d[i] = rsqrtf(fmaxf((float)cnt_d[i], 1.0f));
    }
}

__global__ __launch_bounds__(256) void scatter_kernel(const int* __restrict__ src,
                                                      const int* __restrict__ dst,
                                                      const int* __restrict__ offs,
                                                      int* __restrict__ cursor,
                                                      int* __restrict__ ssrc, int E) {
    int e = blockIdx.x * 256 + threadIdx.x;
    if (e < E) {
        int d = dst[e];
        int pos = atomicAdd(&cursor[d], 1);
        ssrc[offs[d] + pos] = src[e];
    }
}

// ---------------- weight transpose + hi/lo split ----------------
// W1 [300][400] f32 -> W1T hi/lo [448][320] bf16 (zero-padded)
__global__ __launch_bounds__(256) void w1t_kernel(const float* __restrict__ W,
                                                  unsigned short* __restrict__ hi,
                                                  unsigned short* __restrict__ lo) {
    int tid = blockIdx.x * 256 + threadIdx.x;
    if (tid >= N1P * K1) return;
    int n = tid / K1, k = tid - n * K1;
    float v = (n < N1 && k < D0) ? W[k * N1 + n] : 0.f;
    unsigned short h = f2bf(v);
    hi[tid] = h;
    lo[tid] = f2bf(v - bf2f(h));
}

// W2 [400][512] f32 -> W2T hi/lo [512][448] bf16 (zero-padded K)
__global__ __launch_bounds__(256) void w2t_kernel(const float* __restrict__ W,
                                                  unsigned short* __restrict__ hi,
                                                  unsigned short* __restrict__ lo) {
    int tid = blockIdx.x * 256 + threadIdx.x;
    if (tid >= N2 * K2) return;
    int n = tid / K2, k = tid - n * K2;
    float v = (k < N1) ? W[k * N2 + n] : 0.f;
    unsigned short h = f2bf(v);
    hi[tid] = h;
    lo[tid] = f2bf(v - bf2f(h));
}

// ---------------- CSR aggregation + hi/lo split output ----------------
// O[n] = nscale[n] * sum_{s in Nin(n)} X[s] * (SSCALE ? sscale[s] : 1)
// Output: Ohi/Olo [NNP][KP] bf16, zero-padded cols >= D and rows >= NN.
template <int D, int KP, bool SSCALE>
__global__ __launch_bounds__(256) void agg_split_kernel(
    const float* __restrict__ X, const int* __restrict__ offs,
    const int* __restrict__ ssrc, const float* __restrict__ sscale,
    const float* __restrict__ nscale,
    unsigned short* __restrict__ Ohi, unsigned short* __restrict__ Olo) {
    constexpr int C   = D / 4;        // valid float4 chunks per source row (75/100)
    constexpr int CO2 = KP / 4 - 64;  // lanes writing the second output chunk (16/48)
    int node = blockIdx.x * 4 + (threadIdx.x >> 6);
    if (node >= NNP) return;
    int l = threadIdx.x & 63;
    bool g2 = (l + 64) < C;

    float4 a0 = {0.f, 0.f, 0.f, 0.f};
    float4 a1 = {0.f, 0.f, 0.f, 0.f};
    if (node < NN) {
        int start = offs[node], end = offs[node + 1];
        for (int j = start; j < end; ++j) {
            int s = ssrc[j];                               // wave-uniform
            const float4* row = (const float4*)(X + (size_t)s * D);
            float sc = SSCALE ? sscale[s] : 1.0f;
            float4 v = row[l];
            a0.x += v.x * sc; a0.y += v.y * sc; a0.z += v.z * sc; a0.w += v.w * sc;
            if (g2) {
                float4 u = row[l + 64];
                a1.x += u.x * sc; a1.y += u.y * sc; a1.z += u.z * sc; a1.w += u.w * sc;
            }
        }
        float ns = nscale[node];
        a0.x *= ns; a0.y *= ns; a0.z *= ns; a0.w *= ns;
        a1.x *= ns; a1.y *= ns; a1.z *= ns; a1.w *= ns;
    }
    if (!g2) a1 = {0.f, 0.f, 0.f, 0.f};   // pad cols -> exact zeros

    size_t base = (size_t)node * KP;
    {
        unsigned short h0 = f2bf(a0.x), h1 = f2bf(a0.y), h2_ = f2bf(a0.z), h3 = f2bf(a0.w);
        unsigned short hv[4] = {h0, h1, h2_, h3};
        unsigned short lv[4] = {f2bf(a0.x - bf2f(h0)), f2bf(a0.y - bf2f(h1)),
                                f2bf(a0.z - bf2f(h2_)), f2bf(a0.w - bf2f(h3))};
        *(uint2*)(Ohi + base + 4 * l) = *(uint2*)hv;
        *(uint2*)(Olo + base + 4 * l) = *(uint2*)lv;
    }
    if (l < CO2) {
        unsigned short h0 = f2bf(a1.x), h1 = f2bf(a1.y), h2_ = f2bf(a1.z), h3 = f2bf(a1.w);
        unsigned short hv[4] = {h0, h1, h2_, h3};
        unsigned short lv[4] = {f2bf(a1.x - bf2f(h0)), f2bf(a1.y - bf2f(h1)),
                                f2bf(a1.z - bf2f(h2_)), f2bf(a1.w - bf2f(h3))};
        *(uint2*)(Ohi + base + 256 + 4 * l) = *(uint2*)hv;
        *(uint2*)(Olo + base + 256 + 4 * l) = *(uint2*)lv;
    }
}

// ---------------- split-bf16 MFMA GEMM ----------------
// C[m][n] = epi( sum_k (Ahi+Alo)[m][k] * (Bhi+Blo)^T[n][k] )  (3-term bf16x3)
// A: [NNP][Kpad] bf16 hi/lo.  B^T: [Npad][Kpad] bf16 hi/lo (k-contiguous).
// Tile 128x64, BK=64, 256 threads = 4 waves (2x2), wave tile 64x32.
template <bool LRELU_SCALE>
__global__ __launch_bounds__(256) void gemm_mfma_kernel(
    const unsigned short* __restrict__ Ahi, const unsigned short* __restrict__ Alo,
    const unsigned short* __restrict__ Bhi, const unsigned short* __restrict__ Blo,
    const float* __restrict__ bias, const float* __restrict__ rs,
    float* __restrict__ C, int nbn, int Kpad, int Nvalid, int Cld) {
    __shared__ unsigned short lds[24576];     // 48KB: Ahi 8192 | Alo 8192 | Bhi 4096 | Blo 4096
    const int AHI = 0, ALO = 8192, BHI = 16384, BLO = 20480;

    // bijective XCD-chunked swizzle (m204), n-fast decode for A-tile L2 reuse
    int nwg = (int)gridDim.x, orig = (int)blockIdx.x;
    int q8 = nwg >> 3, r8 = nwg & 7;
    int xc = orig & 7, o8 = orig >> 3;
    int wg = (xc < r8 ? xc * (q8 + 1) : r8 * (q8 + 1) + (xc - r8) * q8) + o8;
    int bn = wg % nbn, bm = wg / nbn;
    int m0 = bm * 128, n0 = bn * 64;

    int t = threadIdx.x, l = t & 63, w = t >> 6;
    int wm = w >> 1, wn = w & 1;

    f32x4 acc[4][2] = {};

    for (int k0 = 0; k0 < Kpad; k0 += 64) {
        // stage A tile (128 rows x 64 k) hi+lo: 4 chunks of 16B per thread per array.
        // LDS is linear in chunk order; global k-slot is pre-swizzled (slot ^ (row&7))
        // so that swizzled ds_reads land bank-conflict-free.
#pragma unroll
        for (int j = 0; j < 4; ++j) {
            int c = j * 256 + t;
            int r = c >> 3, qs = c & 7;
            size_t goff = (size_t)(m0 + r) * Kpad + k0 + ((qs ^ (r & 7)) << 3);
            int lbase = (j * 256 + w * 64) * 8;
            __builtin_amdgcn_global_load_lds(
                (const __attribute__((address_space(1))) void*)(Ahi + goff),
                (__attribute__((address_space(3))) void*)&lds[AHI + lbase], 16, 0, 0);
            __builtin_amdgcn_global_load_lds(
                (const __attribute__((address_space(1))) void*)(Alo + goff),
                (__attribute__((address_space(3))) void*)&lds[ALO + lbase], 16, 0, 0);
        }
        // stage B^T tile (64 n-rows x 64 k) hi+lo: 2 chunks per thread per array
#pragma unroll
        for (int j = 0; j < 2; ++j) {
            int c = j * 256 + t;
            int r = c >> 3, qs = c & 7;
            size_t goff = (size_t)(n0 + r) * Kpad + k0 + ((qs ^ (r & 7)) << 3);
            int lbase = (j * 256 + w * 64) * 8;
            __builtin_amdgcn_global_load_lds(
                (const __attribute__((address_space(1))) void*)(Bhi + goff),
                (__attribute__((address_space(3))) void*)&lds[BHI + lbase], 16, 0, 0);
            __builtin_amdgcn_global_load_lds(
                (const __attribute__((address_space(1))) void*)(Blo + goff),
                (__attribute__((address_space(3))) void*)&lds[BLO + lbase], 16, 0, 0);
        }
        __syncthreads();

#pragma unroll
        for (int ks = 0; ks < 2; ++ks) {
            bf16x8 bh[2], bl[2];
#pragma unroll
            for (int ni = 0; ni < 2; ++ni) {
                int n = wn * 32 + ni * 16 + (l & 15);
                int slot = ks * 4 + (l >> 4);
                int idx = n * 64 + ((slot ^ (n & 7)) << 3);
                bh[ni] = *(const bf16x8*)&lds[BHI + idx];
                bl[ni] = *(const bf16x8*)&lds[BLO + idx];
            }
#pragma unroll
            for (int mi = 0; mi < 4; ++mi) {
                int m = wm * 64 + mi * 16 + (l & 15);
                int slot = ks * 4 + (l >> 4);
                int idx = m * 64 + ((slot ^ (m & 7)) << 3);
                bf16x8 ah = *(const bf16x8*)&lds[AHI + idx];
                bf16x8 al = *(const bf16x8*)&lds[ALO + idx];
#pragma unroll
                for (int ni = 0; ni < 2; ++ni) {
                    acc[mi][ni] = __builtin_amdgcn_mfma_f32_16x16x32_bf16(ah, bh[ni], acc[mi][ni], 0, 0, 0);
                    acc[mi][ni] = __builtin_amdgcn_mfma_f32_16x16x32_bf16(ah, bl[ni], acc[mi][ni], 0, 0, 0);
                    acc[mi][ni] = __builtin_amdgcn_mfma_f32_16x16x32_bf16(al, bh[ni], acc[mi][ni], 0, 0, 0);
                }
            }
        }
        __syncthreads();
    }

    // epilogue: C/D layout col = lane&15, row = (lane>>4)*4 + reg  [m89-verified]
#pragma unroll
    for (int mi = 0; mi < 4; ++mi) {
        int mbase = m0 + wm * 64 + mi * 16 + ((l >> 4) << 2);
#pragma unroll
        for (int q = 0; q < 4; ++q) {
            int m = mbase + q;
            if (m >= NN) continue;
            float scale = LRELU_SCALE ? rs[m] : 1.0f;
#pragma unroll
            for (int ni = 0; ni < 2; ++ni) {
                int n = n0 + wn * 32 + ni * 16 + (l & 15);
                if (n >= Nvalid) continue;
                float v = acc[mi][ni][q] + bias[n];
                if (LRELU_SCALE) { v = v >= 0.f ? v : 0.2f * v; v *= scale; }
                C[(size_t)m * Cld + n] = v;
            }
        }
    }
}

extern "C" void kernel_launch(void* const* d_in, const int* in_sizes, int n_in,
                              void* d_out, int out_size, void* d_ws, size_t ws_size,
                              hipStream_t stream) {
    const float* emb = (const float*)d_in[0];
    const float* W1  = (const float*)d_in[1];
    const float* b1  = (const float*)d_in[2];
    const float* W2  = (const float*)d_in[3];
    const float* b2  = (const float*)d_in[4];
    const int*   src = (const int*)d_in[5];
    const int*   dst = (const int*)d_in[6];
    const int E = in_sizes[5];

    // ws: A1 hi/lo (64.1MB) then reused by A2 hi/lo (89.7MB); W2T hi/lo after A2.
    unsigned short* A1hi = (unsigned short*)d_ws;
    unsigned short* A1lo = A1hi + (size_t)NNP * K1;
    unsigned short* A2hi = (unsigned short*)d_ws;
    unsigned short* A2lo = A2hi + (size_t)NNP * K2;
    unsigned short* W2Thi = (unsigned short*)((char*)d_ws + 2 * (size_t)NNP * K2 * 2);
    unsigned short* W2Tlo = W2Thi + (size_t)N2 * K2;
    // total ws: 89.69MB + 1.84MB = 91.5MB

    // d_out: h2 f32 [NN][400] (80MB), then CSR + scales + W1T in the dead tail.
    // All tail data is consumed before the final GEMM overwrites d_out.
    float* out = (float*)d_out;
    float* h2  = out;
    char* tail = (char*)d_out + (size_t)NN * N1 * 4;
    int* cnt_s  = (int*)tail;                // NN
    int* cnt_d  = cnt_s + NN;                // NN
    int* offs   = cnt_d + NN;                // NN+1
    int* cursor = offs + NN + 1;             // NN
    int* ssrc   = cursor + NN;               // E
    float* deg_s = (float*)(ssrc + E);       // NN (out_s)
    float* deg_d = deg_s + NN;               // NN (in_s)
    unsigned short* W1Thi = (unsigned short*)(deg_d + NN);   // N1P*K1
    unsigned short* W1Tlo = W1Thi + (size_t)N1P * K1;
    // tail usage ~= 4.0 + 0.4 + 0.57 MB << 22.4MB

    hipMemsetAsync(cnt_s, 0, (size_t)(4 * NN + 1) * sizeof(int), stream);

    hist_kernel<<<(E + 255) / 256, 256, 0, stream>>>(src, dst, cnt_s, cnt_d, E);
    scan_kernel<<<1, 1024, 0, stream>>>(cnt_d, offs);
    rsqrt_kernel<<<(NN + 255) / 256, 256, 0, stream>>>(cnt_s, cnt_d, deg_s, deg_d, NN);
    scatter_kernel<<<(E + 255) / 256, 256, 0, stream>>>(src, dst, offs, cursor, ssrc, E);

    w1t_kernel<<<(N1P * K1 + 255) / 256, 256, 0, stream>>>(W1, W1Thi, W1Tlo);
    w2t_kernel<<<(N2 * K2 + 255) / 256, 256, 0, stream>>>(W2, W2Thi, W2Tlo);

    // layer 1: A1[n] = in_s[n] * sum emb[s]*out_s[s]  -> hi/lo bf16 [NNP][320]
    agg_split_kernel<D0, K1, true><<<NNP / 4, 256, 0, stream>>>(
        emb, offs, ssrc, deg_s, deg_d, A1hi, A1lo);

    // h2 = lrelu(A1 @ W1 + b1) * out_s   (f32, [NN][400])
    gemm_mfma_kernel<true><<<391 * 7, 256, 0, stream>>>(
        A1hi, A1lo, W1Thi, W1Tlo, b1, deg_s, h2, 7, K1, N1, N1);

    // layer 2: A2[n] = in_s[n] * sum h2[s]  -> hi/lo bf16 [NNP][448]
    agg_split_kernel<N1, K2, false><<<NNP / 4, 256, 0, stream>>>(
        h2, offs, ssrc, nullptr, deg_d, A2hi, A2lo);

    // out = A2 @ W2 + b2   (f32, [NN][512])
    gemm_mfma_kernel<false><<<391 * 8, 256, 0, stream>>>(
        A2hi, A2lo, W2Thi, W2Tlo, b2, nullptr, out, 8, K2, N2, N2);
}

// Round 5
// 562.991 us; speedup vs baseline: 14.4850x; 1.2601x over previous
//
#include <hip/hip_runtime.h>
#include <hip/hip_fp16.h>

#define NN   50000      // nodes
#define NNP  50048      // padded to 128-multiple (391 * 128)
#define D0   300        // emb dim
#define K1   320        // D0 padded to 64-multiple
#define N1   400        // layer-1 out dim
#define K2   448        // N1 padded to 64-multiple (= GEMM2 K)
#define N2   512        // layer-2 out dim

typedef __attribute__((ext_vector_type(8))) short bf16x8;
typedef __attribute__((ext_vector_type(4))) float f32x4;

__device__ __forceinline__ unsigned short f2bf(float x) {   // rn-even f32->bf16
    union { float f; unsigned u; } v; v.f = x;
    unsigned r = v.u + 0x7fffu + ((v.u >> 16) & 1u);
    return (unsigned short)(r >> 16);
}

// ---------------- CSR build ----------------
__global__ __launch_bounds__(256) void hist_kernel(const int* __restrict__ src,
                                                   const int* __restrict__ dst,
                                                   int* __restrict__ cnt_s,
                                                   int* __restrict__ cnt_d, int E) {
    int e = blockIdx.x * 256 + threadIdx.x;
    if (e < E) {
        atomicAdd(&cnt_s[src[e]], 1);
        atomicAdd(&cnt_d[dst[e]], 1);
    }
}

__global__ __launch_bounds__(1024) void scan_kernel(const int* __restrict__ cnt,
                                                    int* __restrict__ offs) {
    __shared__ int sums[1024];
    const int PER = (NN + 1023) / 1024;
    int tid = threadIdx.x;
    int base = tid * PER;
    int s = 0;
    for (int i = 0; i < PER; ++i) {
        int idx = base + i;
        if (idx < NN) s += cnt[idx];
    }
    sums[tid] = s;
    __syncthreads();
    for (int off = 1; off < 1024; off <<= 1) {
        int v = (tid >= off) ? sums[tid - off] : 0;
        __syncthreads();
        sums[tid] += v;
        __syncthreads();
    }
    int run = (tid > 0) ? sums[tid - 1] : 0;
    for (int i = 0; i < PER; ++i) {
        int idx = base + i;
        if (idx < NN) { offs[idx] = run; run += cnt[idx]; }
    }
    if (tid == 1023) offs[NN] = sums[1023];
}

__global__ __launch_bounds__(256) void rsqrt_kernel(const int* __restrict__ cnt_s,
                                                    const int* __restrict__ cnt_d,
                                                    float* __restrict__ deg_s,
                                                    float* __restrict__ deg_d, int n) {
    int i = blockIdx.x * 256 + threadIdx.x;
    if (i < n) {
        deg_s[i] = rsqrtf(fmaxf((float)cnt_s[i], 1.0f));
        deg_d[i] = rsqrtf(fmaxf((float)cnt_d[i], 1.0f));
    }
}

__global__ __launch_bounds__(256) void scatter_kernel(const int* __restrict__ src,
                                                      const int* __restrict__ dst,
                                                      const int* __restrict__ offs,
                                                      int* __restrict__ cursor,
                                                      int* __restrict__ ssrc, int E) {
    int e = blockIdx.x * 256 + threadIdx.x;
    if (e < E) {
        int d = dst[e];
        int pos = atomicAdd(&cursor[d], 1);
        ssrc[offs[d] + pos] = src[e];
    }
}

// ---------------- emb f32 -> fp16 ----------------
__global__ __launch_bounds__(256) void embh_kernel(const float* __restrict__ emb,
                                                   __half* __restrict__ embh) {
    int tid = blockIdx.x * 256 + threadIdx.x;
    const int total = NN * D0 / 4;
    if (tid >= total) return;
    float4 v = ((const float4*)emb)[tid];
    __half h[4] = {__float2half(v.x), __float2half(v.y), __float2half(v.z), __float2half(v.w)};
    *(uint2*)(embh + 4 * (size_t)tid) = *(uint2*)h;
}

// ---------------- weight transpose -> bf16 ----------------
__global__ __launch_bounds__(256) void w1t_kernel(const float* __restrict__ W,
                                                  unsigned short* __restrict__ T) {
    int tid = blockIdx.x * 256 + threadIdx.x;
    if (tid >= K2 * K1) return;               // [448][320]
    int n = tid / K1, k = tid - n * K1;
    float v = (n < N1 && k < D0) ? W[k * N1 + n] : 0.f;
    T[tid] = f2bf(v);
}

__global__ __launch_bounds__(256) void w2t_kernel(const float* __restrict__ W,
                                                  unsigned short* __restrict__ T) {
    int tid = blockIdx.x * 256 + threadIdx.x;
    if (tid >= N2 * K2) return;               // [512][448]
    int n = tid / K2, k = tid - n * K2;
    float v = (k < N1) ? W[k * N2 + n] : 0.f;
    T[tid] = f2bf(v);
}

// ---------------- CSR aggregation (fp16 in, bf16 out) ----------------
// O[n][:] = bf16( nscale[n] * sum_{s in Nin(n)} X[s][:] * (SSCALE?sscale[s]:1) )
// X: fp16 rows of D elems. O: [NNP][KP] bf16, zero-padded.
template <int D, int KP, bool SSCALE>
__global__ __launch_bounds__(256) void agg_h_kernel(
    const __half* __restrict__ X, const int* __restrict__ offs,
    const int* __restrict__ ssrc, const float* __restrict__ sscale,
    const float* __restrict__ nscale, unsigned short* __restrict__ O) {
    constexpr int CH  = D / 4;        // 4-half chunks per source row (75 / 100)
    constexpr int CO2 = KP / 4 - 64;  // lanes writing second output chunk (16 / 48)
    int node = blockIdx.x * 4 + (threadIdx.x >> 6);
    if (node >= NNP) return;
    int l = threadIdx.x & 63;
    bool g2 = (l + 64) < CH;

    float a0[4] = {0.f, 0.f, 0.f, 0.f};
    float a1[4] = {0.f, 0.f, 0.f, 0.f};
    if (node < NN) {
        int start = offs[node], end = offs[node + 1];
        for (int j = start; j < end; ++j) {
            int s = ssrc[j];                               // wave-uniform
            const __half* row = X + (size_t)s * D;
            float sc = SSCALE ? sscale[s] : 1.0f;
            uint2 u = *(const uint2*)(row + 4 * l);
            __half2 p0 = *(__half2*)&u.x, p1 = *(__half2*)&u.y;
            float2 f0 = __half22float2(p0), f1 = __half22float2(p1);
            a0[0] += f0.x * sc; a0[1] += f0.y * sc; a0[2] += f1.x * sc; a0[3] += f1.y * sc;
            if (g2) {
                uint2 w = *(const uint2*)(row + 4 * (l + 64));
                __half2 q0 = *(__half2*)&w.x, q1 = *(__half2*)&w.y;
                float2 g0 = __half22float2(q0), g1 = __half22float2(q1);
                a1[0] += g0.x * sc; a1[1] += g0.y * sc; a1[2] += g1.x * sc; a1[3] += g1.y * sc;
            }
        }
        float ns = nscale[node];
#pragma unroll
        for (int i = 0; i < 4; ++i) { a0[i] *= ns; a1[i] *= ns; }
    }

    size_t base = (size_t)node * KP;
    {
        unsigned short hv[4] = {f2bf(a0[0]), f2bf(a0[1]), f2bf(a0[2]), f2bf(a0[3])};
        *(uint2*)(O + base + 4 * l) = *(uint2*)hv;
    }
    if (l < CO2) {
        unsigned short hv[4] = {f2bf(a1[0]), f2bf(a1[1]), f2bf(a1[2]), f2bf(a1[3])};
        *(uint2*)(O + base + 256 + 4 * l) = *(uint2*)hv;
    }
}

// ---------------- pure-bf16 MFMA GEMM ----------------
// C[m][n] = epi( sum_k A[m][k] * BT[n][k] ), A [NNP][Kpad], BT [Npad][Kpad] bf16.
// Tile 128x64, BK=64, 4 waves (2x2), wave tile 64x32.
// WRITE_HALF: C is fp16 (h2 path, with lrelu*rs); else f32 plain.
template <bool LRELU_SCALE, bool WRITE_HALF>
__global__ __launch_bounds__(256) void gemm_bf16_kernel(
    const unsigned short* __restrict__ A, const unsigned short* __restrict__ BT,
    const float* __restrict__ bias, const float* __restrict__ rs,
    void* __restrict__ Cv, int nbn, int Kpad, int Nvalid, int Cld) {
    __shared__ unsigned short lds[12288];     // 24KB: A 8192 shorts | B 4096 shorts
    const int AOF = 0, BOF = 8192;

    // bijective XCD-chunked swizzle, n-fast decode for A-tile L2 reuse
    int nwg = (int)gridDim.x, orig = (int)blockIdx.x;
    int q8 = nwg >> 3, r8 = nwg & 7;
    int xc = orig & 7, o8 = orig >> 3;
    int wg = (xc < r8 ? xc * (q8 + 1) : r8 * (q8 + 1) + (xc - r8) * q8) + o8;
    int bn = wg % nbn, bm = wg / nbn;
    int m0 = bm * 128, n0 = bn * 64;

    int t = threadIdx.x, l = t & 63, w = t >> 6;
    int wm = w >> 1, wn = w & 1;

    f32x4 acc[4][2] = {};

    for (int k0 = 0; k0 < Kpad; k0 += 64) {
        // stage A tile (128 x 64) : 4 x 16B chunks per thread; pre-swizzled global k-slot
#pragma unroll
        for (int j = 0; j < 4; ++j) {
            int c = j * 256 + t;
            int r = c >> 3, qs = c & 7;
            size_t goff = (size_t)(m0 + r) * Kpad + k0 + ((qs ^ (r & 7)) << 3);
            int lbase = (j * 256 + w * 64) * 8;
            __builtin_amdgcn_global_load_lds(
                (const __attribute__((address_space(1))) void*)(A + goff),
                (__attribute__((address_space(3))) void*)&lds[AOF + lbase], 16, 0, 0);
        }
        // stage B^T tile (64 x 64): 2 chunks per thread
#pragma unroll
        for (int j = 0; j < 2; ++j) {
            int c = j * 256 + t;
            int r = c >> 3, qs = c & 7;
            size_t goff = (size_t)(n0 + r) * Kpad + k0 + ((qs ^ (r & 7)) << 3);
            int lbase = (j * 256 + w * 64) * 8;
            __builtin_amdgcn_global_load_lds(
                (const __attribute__((address_space(1))) void*)(BT + goff),
                (__attribute__((address_space(3))) void*)&lds[BOF + lbase], 16, 0, 0);
        }
        __syncthreads();

#pragma unroll
        for (int ks = 0; ks < 2; ++ks) {
            bf16x8 bfr[2];
#pragma unroll
            for (int ni = 0; ni < 2; ++ni) {
                int n = wn * 32 + ni * 16 + (l & 15);
                int slot = ks * 4 + (l >> 4);
                int idx = n * 64 + ((slot ^ (n & 7)) << 3);
                bfr[ni] = *(const bf16x8*)&lds[BOF + idx];
            }
#pragma unroll
            for (int mi = 0; mi < 4; ++mi) {
                int m = wm * 64 + mi * 16 + (l & 15);
                int slot = ks * 4 + (l >> 4);
                int idx = m * 64 + ((slot ^ (m & 7)) << 3);
                bf16x8 afr = *(const bf16x8*)&lds[AOF + idx];
#pragma unroll
                for (int ni = 0; ni < 2; ++ni)
                    acc[mi][ni] = __builtin_amdgcn_mfma_f32_16x16x32_bf16(afr, bfr[ni], acc[mi][ni], 0, 0, 0);
            }
        }
        __syncthreads();
    }

    // epilogue: C/D layout col = lane&15, row = (lane>>4)*4 + reg
#pragma unroll
    for (int mi = 0; mi < 4; ++mi) {
        int mbase = m0 + wm * 64 + mi * 16 + ((l >> 4) << 2);
#pragma unroll
        for (int q = 0; q < 4; ++q) {
            int m = mbase + q;
            if (m >= NN) continue;
            float scale = LRELU_SCALE ? rs[m] : 1.0f;
#pragma unroll
            for (int ni = 0; ni < 2; ++ni) {
                int n = n0 + wn * 32 + ni * 16 + (l & 15);
                if (n >= Nvalid) continue;
                float v = acc[mi][ni][q] + bias[n];
                if (LRELU_SCALE) { v = v >= 0.f ? v : 0.2f * v; v *= scale; }
                if (WRITE_HALF)
                    ((__half*)Cv)[(size_t)m * Cld + n] = __float2half(v);
                else
                    ((float*)Cv)[(size_t)m * Cld + n] = v;
            }
        }
    }
}

extern "C" void kernel_launch(void* const* d_in, const int* in_sizes, int n_in,
                              void* d_out, int out_size, void* d_ws, size_t ws_size,
                              hipStream_t stream) {
    const float* emb = (const float*)d_in[0];
    const float* W1  = (const float*)d_in[1];
    const float* b1  = (const float*)d_in[2];
    const float* W2  = (const float*)d_in[3];
    const float* b2  = (const float*)d_in[4];
    const int*   src = (const int*)d_in[5];
    const int*   dst = (const int*)d_in[6];
    const int E = in_sizes[5];

    // ws layout (77.7MB total):
    //   [0, 32.0MB)      A1 bf16 [NNP][320]
    //   [32.0, 76.9MB)   A2 bf16 [NNP][448]; embh fp16 [NN][300] (30MB) overlaps
    //                    A2's region but is dead before agg2 writes A2.
    //   [76.9MB, ...)    W1T bf16 [448][320], W2T bf16 [512][448]
    unsigned short* A1   = (unsigned short*)d_ws;
    unsigned short* A2   = A1 + (size_t)NNP * K1;
    __half*         embh = (__half*)A2;
    unsigned short* W1T  = A2 + (size_t)NNP * K2;
    unsigned short* W2T  = W1T + (size_t)K2 * K1;

    // d_out layout: h2 fp16 [NN][400] (40MB) | CSR + scales tail (4.4MB).
    // Everything here is dead before the final GEMM overwrites d_out.
    __half* h2  = (__half*)d_out;
    float*  out = (float*)d_out;
    char* tail = (char*)d_out + (size_t)NN * N1 * sizeof(__half);
    int* cnt_s  = (int*)tail;                // NN
    int* cnt_d  = cnt_s + NN;                // NN
    int* offs   = cnt_d + NN;                // NN+1
    int* cursor = offs + NN + 1;             // NN
    int* ssrc   = cursor + NN;               // E
    float* deg_s = (float*)(ssrc + E);       // NN (out_s)
    float* deg_d = deg_s + NN;               // NN (in_s)

    hipMemsetAsync(cnt_s, 0, (size_t)(4 * NN + 1) * sizeof(int), stream);

    hist_kernel<<<(E + 255) / 256, 256, 0, stream>>>(src, dst, cnt_s, cnt_d, E);
    scan_kernel<<<1, 1024, 0, stream>>>(cnt_d, offs);
    rsqrt_kernel<<<(NN + 255) / 256, 256, 0, stream>>>(cnt_s, cnt_d, deg_s, deg_d, NN);
    scatter_kernel<<<(E + 255) / 256, 256, 0, stream>>>(src, dst, offs, cursor, ssrc, E);

    embh_kernel<<<(NN * D0 / 4 + 255) / 256, 256, 0, stream>>>(emb, embh);
    w1t_kernel<<<(K2 * K1 + 255) / 256, 256, 0, stream>>>(W1, W1T);
    w2t_kernel<<<(N2 * K2 + 255) / 256, 256, 0, stream>>>(W2, W2T);

    // layer 1: A1[n] = bf16( in_s[n] * sum emb_h[s]*out_s[s] )
    agg_h_kernel<D0, K1, true><<<NNP / 4, 256, 0, stream>>>(
        embh, offs, ssrc, deg_s, deg_d, A1);

    // h2 = fp16( lrelu(A1 @ W1 + b1) * out_s )
    gemm_bf16_kernel<true, true><<<391 * 7, 256, 0, stream>>>(
        A1, W1T, b1, deg_s, h2, 7, K1, N1, N1);

    // layer 2: A2[n] = bf16( in_s[n] * sum h2[s] )
    agg_h_kernel<N1, K2, false><<<NNP / 4, 256, 0, stream>>>(
        h2, offs, ssrc, nullptr, deg_d, A2);

    // out = A2 @ W2 + b2   (f32)
    gemm_bf16_kernel<false, false><<<391 * 8, 256, 0, stream>>>(
        A2, W2T, b2, nullptr, out, 8, K2, N2, N2);
}

// Round 6
// 489.529 us; speedup vs baseline: 16.6587x; 1.1501x over previous
//
#include <hip/hip_runtime.h>
#include <hip/hip_fp16.h>

#define NN   50000      // nodes
#define NNP  50048      // padded to 128-multiple (391 * 128)
#define D0   300        // emb dim
#define K1   320        // D0 padded to 64-multiple
#define N1   400        // layer-1 out dim
#define K2   448        // N1 padded to 64-multiple (= GEMM2 K)
#define N2   512        // layer-2 out dim

typedef __attribute__((ext_vector_type(8))) short bf16x8;
typedef __attribute__((ext_vector_type(4))) float f32x4;

__device__ __forceinline__ unsigned short f2bf(float x) {   // rn-even f32->bf16
    union { float f; unsigned u; } v; v.f = x;
    unsigned r = v.u + 0x7fffu + ((v.u >> 16) & 1u);
    return (unsigned short)(r >> 16);
}

// ---------------- CSR build ----------------
__global__ __launch_bounds__(256) void hist_kernel(const int* __restrict__ src,
                                                   const int* __restrict__ dst,
                                                   int* __restrict__ cnt_s,
                                                   int* __restrict__ cnt_d, int E) {
    int e = blockIdx.x * 256 + threadIdx.x;
    if (e < E) {
        atomicAdd(&cnt_s[src[e]], 1);
        atomicAdd(&cnt_d[dst[e]], 1);
    }
}

__global__ __launch_bounds__(1024) void scan_kernel(const int* __restrict__ cnt,
                                                    int* __restrict__ offs) {
    __shared__ int sums[1024];
    const int PER = (NN + 1023) / 1024;
    int tid = threadIdx.x;
    int base = tid * PER;
    int s = 0;
    for (int i = 0; i < PER; ++i) {
        int idx = base + i;
        if (idx < NN) s += cnt[idx];
    }
    sums[tid] = s;
    __syncthreads();
    for (int off = 1; off < 1024; off <<= 1) {
        int v = (tid >= off) ? sums[tid - off] : 0;
        __syncthreads();
        sums[tid] += v;
        __syncthreads();
    }
    int run = (tid > 0) ? sums[tid - 1] : 0;
    for (int i = 0; i < PER; ++i) {
        int idx = base + i;
        if (idx < NN) { offs[idx] = run; run += cnt[idx]; }
    }
    if (tid == 1023) offs[NN] = sums[1023];
}

__global__ __launch_bounds__(256) void rsqrt_kernel(const int* __restrict__ cnt_s,
                                                    const int* __restrict__ cnt_d,
                                                    float* __restrict__ deg_s,
                                                    float* __restrict__ deg_d, int n) {
    int i = blockIdx.x * 256 + threadIdx.x;
    if (i < n) {
        deg_s[i] = rsqrtf(fmaxf((float)cnt_s[i], 1.0f));
        deg_d[i] = rsqrtf(fmaxf((float)cnt_d[i], 1.0f));
    }
}

__global__ __launch_bounds__(256) void scatter_kernel(const int* __restrict__ src,
                                                      const int* __restrict__ dst,
                                                      const int* __restrict__ offs,
                                                      int* __restrict__ cursor,
                                                      int* __restrict__ ssrc, int E) {
    int e = blockIdx.x * 256 + threadIdx.x;
    if (e < E) {
        int d = dst[e];
        int pos = atomicAdd(&cursor[d], 1);
        ssrc[offs[d] + pos] = src[e];
    }
}

// ---------------- emb f32 -> fp16, fused with out_s row scale ----------------
__global__ __launch_bounds__(256) void embh_kernel(const float* __restrict__ emb,
                                                   const float* __restrict__ deg_s,
                                                   __half* __restrict__ embh) {
    int tid = blockIdx.x * 256 + threadIdx.x;
    const int total = NN * (D0 / 4);
    if (tid >= total) return;
    int node = tid / (D0 / 4);                 // magic-mul div by 75
    float sc = deg_s[node];
    float4 v = ((const float4*)emb)[tid];
    __half h[4] = {__float2half(v.x * sc), __float2half(v.y * sc),
                   __float2half(v.z * sc), __float2half(v.w * sc)};
    *(uint2*)(embh + 4 * (size_t)tid) = *(uint2*)h;
}

// ---------------- weight transpose -> bf16 ----------------
__global__ __launch_bounds__(256) void w1t_kernel(const float* __restrict__ W,
                                                  unsigned short* __restrict__ T) {
    int tid = blockIdx.x * 256 + threadIdx.x;
    if (tid >= K2 * K1) return;               // [448][320]
    int n = tid / K1, k = tid - n * K1;
    float v = (n < N1 && k < D0) ? W[k * N1 + n] : 0.f;
    T[tid] = f2bf(v);
}

__global__ __launch_bounds__(256) void w2t_kernel(const float* __restrict__ W,
                                                  unsigned short* __restrict__ T) {
    int tid = blockIdx.x * 256 + threadIdx.x;
    if (tid >= N2 * K2) return;               // [512][448]
    int n = tid / K2, k = tid - n * K2;
    float v = (k < N1) ? W[k * N2 + n] : 0.f;
    T[tid] = f2bf(v);
}

// ---------------- CSR aggregation (fp16 in, bf16 out), unroll x4 ----------------
// O[n][:] = bf16( nscale[n] * sum_{s in Nin(n)} X[s][:] )
// X: fp16 rows of D elems. O: [NNP][KP] bf16, zero-padded.
template <int D, int KP>
__global__ __launch_bounds__(256) void agg_h_kernel(
    const __half* __restrict__ X, const int* __restrict__ offs,
    const int* __restrict__ ssrc, const float* __restrict__ nscale,
    unsigned short* __restrict__ O) {
    constexpr int CH  = D / 4;        // 4-half chunks per source row (75 / 100)
    constexpr int CO2 = KP / 4 - 64;  // lanes writing second output chunk (16 / 48)
    int node = blockIdx.x * 4 + (threadIdx.x >> 6);
    if (node >= NNP) return;
    int l = threadIdx.x & 63;
    bool g2 = (l + 64) < CH;

    float a0[4] = {0.f, 0.f, 0.f, 0.f};
    float a1[4] = {0.f, 0.f, 0.f, 0.f};

#define ACC0(U) { __half2 p0 = *(__half2*)&(U).x, p1 = *(__half2*)&(U).y;          \
                  float2 f0 = __half22float2(p0), f1 = __half22float2(p1);         \
                  a0[0] += f0.x; a0[1] += f0.y; a0[2] += f1.x; a0[3] += f1.y; }
#define ACC1(U) { __half2 p0 = *(__half2*)&(U).x, p1 = *(__half2*)&(U).y;          \
                  float2 f0 = __half22float2(p0), f1 = __half22float2(p1);         \
                  a1[0] += f0.x; a1[1] += f0.y; a1[2] += f1.x; a1[3] += f1.y; }

    if (node < NN) {
        int j = offs[node], end = offs[node + 1];
        // 4-wide software pipeline: issue all gathers before any accumulate
        for (; j + 4 <= end; j += 4) {
            int s0 = ssrc[j], s1 = ssrc[j + 1], s2 = ssrc[j + 2], s3 = ssrc[j + 3];
            const __half* r0 = X + (size_t)s0 * D;
            const __half* r1 = X + (size_t)s1 * D;
            const __half* r2 = X + (size_t)s2 * D;
            const __half* r3 = X + (size_t)s3 * D;
            uint2 u0 = *(const uint2*)(r0 + 4 * l);
            uint2 u1 = *(const uint2*)(r1 + 4 * l);
            uint2 u2 = *(const uint2*)(r2 + 4 * l);
            uint2 u3 = *(const uint2*)(r3 + 4 * l);
            uint2 v0, v1, v2, v3;
            if (g2) {
                v0 = *(const uint2*)(r0 + 4 * (l + 64));
                v1 = *(const uint2*)(r1 + 4 * (l + 64));
                v2 = *(const uint2*)(r2 + 4 * (l + 64));
                v3 = *(const uint2*)(r3 + 4 * (l + 64));
            }
            ACC0(u0); ACC0(u1); ACC0(u2); ACC0(u3);
            if (g2) { ACC1(v0); ACC1(v1); ACC1(v2); ACC1(v3); }
        }
        for (; j < end; ++j) {
            const __half* r = X + (size_t)ssrc[j] * D;
            uint2 u = *(const uint2*)(r + 4 * l);
            ACC0(u);
            if (g2) { uint2 v = *(const uint2*)(r + 4 * (l + 64)); ACC1(v); }
        }
        float ns = nscale[node];
#pragma unroll
        for (int i = 0; i < 4; ++i) { a0[i] *= ns; a1[i] *= ns; }
    }
#undef ACC0
#undef ACC1

    size_t base = (size_t)node * KP;
    {
        unsigned short hv[4] = {f2bf(a0[0]), f2bf(a0[1]), f2bf(a0[2]), f2bf(a0[3])};
        *(uint2*)(O + base + 4 * l) = *(uint2*)hv;
    }
    if (l < CO2) {
        unsigned short hv[4] = {f2bf(a1[0]), f2bf(a1[1]), f2bf(a1[2]), f2bf(a1[3])};
        *(uint2*)(O + base + 256 + 4 * l) = *(uint2*)hv;
    }
}

// ---------------- pure-bf16 MFMA GEMM ----------------
// C[m][n] = epi( sum_k A[m][k] * BT[n][k] ), A [NNP][Kpad], BT [Npad][Kpad] bf16.
// Tile 128x64, BK=64, 4 waves (2x2), wave tile 64x32.
// WRITE_HALF: C is fp16 (h2 path, with lrelu*rs); else f32 plain.
template <bool LRELU_SCALE, bool WRITE_HALF>
__global__ __launch_bounds__(256) void gemm_bf16_kernel(
    const unsigned short* __restrict__ A, const unsigned short* __restrict__ BT,
    const float* __restrict__ bias, const float* __restrict__ rs,
    void* __restrict__ Cv, int nbn, int Kpad, int Nvalid, int Cld) {
    __shared__ unsigned short lds[12288];     // 24KB: A 8192 shorts | B 4096 shorts
    const int AOF = 0, BOF = 8192;

    // bijective XCD-chunked swizzle, n-fast decode for A-tile L2 reuse
    int nwg = (int)gridDim.x, orig = (int)blockIdx.x;
    int q8 = nwg >> 3, r8 = nwg & 7;
    int xc = orig & 7, o8 = orig >> 3;
    int wg = (xc < r8 ? xc * (q8 + 1) : r8 * (q8 + 1) + (xc - r8) * q8) + o8;
    int bn = wg % nbn, bm = wg / nbn;
    int m0 = bm * 128, n0 = bn * 64;

    int t = threadIdx.x, l = t & 63, w = t >> 6;
    int wm = w >> 1, wn = w & 1;

    f32x4 acc[4][2] = {};

    for (int k0 = 0; k0 < Kpad; k0 += 64) {
        // stage A tile (128 x 64): 4 x 16B chunks per thread; pre-swizzled global k-slot
#pragma unroll
        for (int j = 0; j < 4; ++j) {
            int c = j * 256 + t;
            int r = c >> 3, qs = c & 7;
            size_t goff = (size_t)(m0 + r) * Kpad + k0 + ((qs ^ (r & 7)) << 3);
            int lbase = (j * 256 + w * 64) * 8;
            __builtin_amdgcn_global_load_lds(
                (const __attribute__((address_space(1))) void*)(A + goff),
                (__attribute__((address_space(3))) void*)&lds[AOF + lbase], 16, 0, 0);
        }
        // stage B^T tile (64 x 64): 2 chunks per thread
#pragma unroll
        for (int j = 0; j < 2; ++j) {
            int c = j * 256 + t;
            int r = c >> 3, qs = c & 7;
            size_t goff = (size_t)(n0 + r) * Kpad + k0 + ((qs ^ (r & 7)) << 3);
            int lbase = (j * 256 + w * 64) * 8;
            __builtin_amdgcn_global_load_lds(
                (const __attribute__((address_space(1))) void*)(BT + goff),
                (__attribute__((address_space(3))) void*)&lds[BOF + lbase], 16, 0, 0);
        }
        __syncthreads();

#pragma unroll
        for (int ks = 0; ks < 2; ++ks) {
            bf16x8 bfr[2];
#pragma unroll
            for (int ni = 0; ni < 2; ++ni) {
                int n = wn * 32 + ni * 16 + (l & 15);
                int slot = ks * 4 + (l >> 4);
                int idx = n * 64 + ((slot ^ (n & 7)) << 3);
                bfr[ni] = *(const bf16x8*)&lds[BOF + idx];
            }
#pragma unroll
            for (int mi = 0; mi < 4; ++mi) {
                int m = wm * 64 + mi * 16 + (l & 15);
                int slot = ks * 4 + (l >> 4);
                int idx = m * 64 + ((slot ^ (m & 7)) << 3);
                bf16x8 afr = *(const bf16x8*)&lds[AOF + idx];
#pragma unroll
                for (int ni = 0; ni < 2; ++ni)
                    acc[mi][ni] = __builtin_amdgcn_mfma_f32_16x16x32_bf16(afr, bfr[ni], acc[mi][ni], 0, 0, 0);
            }
        }
        __syncthreads();
    }

    // epilogue: C/D layout col = lane&15, row = (lane>>4)*4 + reg
#pragma unroll
    for (int mi = 0; mi < 4; ++mi) {
        int mbase = m0 + wm * 64 + mi * 16 + ((l >> 4) << 2);
#pragma unroll
        for (int q = 0; q < 4; ++q) {
            int m = mbase + q;
            if (m >= NN) continue;
            float scale = LRELU_SCALE ? rs[m] : 1.0f;
#pragma unroll
            for (int ni = 0; ni < 2; ++ni) {
                int n = n0 + wn * 32 + ni * 16 + (l & 15);
                if (n >= Nvalid) continue;
                float v = acc[mi][ni][q] + bias[n];
                if (LRELU_SCALE) { v = v >= 0.f ? v : 0.2f * v; v *= scale; }
                if (WRITE_HALF)
                    ((__half*)Cv)[(size_t)m * Cld + n] = __float2half(v);
                else
                    ((float*)Cv)[(size_t)m * Cld + n] = v;
            }
        }
    }
}

extern "C" void kernel_launch(void* const* d_in, const int* in_sizes, int n_in,
                              void* d_out, int out_size, void* d_ws, size_t ws_size,
                              hipStream_t stream) {
    const float* emb = (const float*)d_in[0];
    const float* W1  = (const float*)d_in[1];
    const float* b1  = (const float*)d_in[2];
    const float* W2  = (const float*)d_in[3];
    const float* b2  = (const float*)d_in[4];
    const int*   src = (const int*)d_in[5];
    const int*   dst = (const int*)d_in[6];
    const int E = in_sizes[5];

    // ws layout (77.7MB total):
    //   [0, 32.0MB)      A1 bf16 [NNP][320]
    //   [32.0, 76.9MB)   A2 bf16 [NNP][448]; embh fp16 [NN][300] (30MB) overlaps
    //                    A2's region but is dead before agg2 writes A2.
    //   [76.9MB, ...)    W1T bf16 [448][320], W2T bf16 [512][448]
    unsigned short* A1   = (unsigned short*)d_ws;
    unsigned short* A2   = A1 + (size_t)NNP * K1;
    __half*         embh = (__half*)A2;
    unsigned short* W1T  = A2 + (size_t)NNP * K2;
    unsigned short* W2T  = W1T + (size_t)K2 * K1;

    // d_out layout: h2 fp16 [NN][400] (40MB) | CSR + scales tail (4.4MB).
    // Everything here is dead before the final GEMM overwrites d_out.
    __half* h2  = (__half*)d_out;
    float*  out = (float*)d_out;
    char* tail = (char*)d_out + (size_t)NN * N1 * sizeof(__half);
    int* cnt_s  = (int*)tail;                // NN
    int* cnt_d  = cnt_s + NN;                // NN
    int* offs   = cnt_d + NN;                // NN+1
    int* cursor = offs + NN + 1;             // NN
    int* ssrc   = cursor + NN;               // E
    float* deg_s = (float*)(ssrc + E);       // NN (out_s)
    float* deg_d = deg_s + NN;               // NN (in_s)

    hipMemsetAsync(cnt_s, 0, (size_t)(4 * NN + 1) * sizeof(int), stream);

    hist_kernel<<<(E + 255) / 256, 256, 0, stream>>>(src, dst, cnt_s, cnt_d, E);
    scan_kernel<<<1, 1024, 0, stream>>>(cnt_d, offs);
    rsqrt_kernel<<<(NN + 255) / 256, 256, 0, stream>>>(cnt_s, cnt_d, deg_s, deg_d, NN);
    scatter_kernel<<<(E + 255) / 256, 256, 0, stream>>>(src, dst, offs, cursor, ssrc, E);

    // embh = fp16(emb * out_s)  (out_s fused here, so agg1 needs no src scale)
    embh_kernel<<<(NN * (D0 / 4) + 255) / 256, 256, 0, stream>>>(emb, deg_s, embh);
    w1t_kernel<<<(K2 * K1 + 255) / 256, 256, 0, stream>>>(W1, W1T);
    w2t_kernel<<<(N2 * K2 + 255) / 256, 256, 0, stream>>>(W2, W2T);

    // layer 1: A1[n] = bf16( in_s[n] * sum embh[s] )
    agg_h_kernel<D0, K1><<<NNP / 4, 256, 0, stream>>>(embh, offs, ssrc, deg_d, A1);

    // h2 = fp16( lrelu(A1 @ W1 + b1) * out_s )
    gemm_bf16_kernel<true, true><<<391 * 7, 256, 0, stream>>>(
        A1, W1T, b1, deg_s, h2, 7, K1, N1, N1);

    // layer 2: A2[n] = bf16( in_s[n] * sum h2[s] )
    agg_h_kernel<N1, K2><<<NNP / 4, 256, 0, stream>>>(h2, offs, ssrc, deg_d, A2);

    // out = A2 @ W2 + b2   (f32)
    gemm_bf16_kernel<false, false><<<391 * 8, 256, 0, stream>>>(
        A2, W2T, b2, nullptr, out, 8, K2, N2, N2);
}

// Round 7
// 482.791 us; speedup vs baseline: 16.8912x; 1.0140x over previous
//
#include <hip/hip_runtime.h>
#include <hip/hip_fp16.h>

#define NN   50000      // nodes
#define NNP  50048      // padded to 128-multiple (391 * 128)
#define D0   300        // emb dim
#define K1   320        // D0 padded to 64-multiple (embh row stride too)
#define N1   400        // layer-1 out dim
#define K2   448        // N1 padded to 64-multiple (= GEMM2 K)
#define N2   512        // layer-2 out dim

typedef __attribute__((ext_vector_type(8))) short bf16x8;
typedef __attribute__((ext_vector_type(4))) float f32x4;

__device__ __forceinline__ unsigned short f2bf(float x) {   // rn-even f32->bf16
    union { float f; unsigned u; } v; v.f = x;
    unsigned r = v.u + 0x7fffu + ((v.u >> 16) & 1u);
    return (unsigned short)(r >> 16);
}

// ---------------- CSR build ----------------
__global__ __launch_bounds__(256) void hist_kernel(const int* __restrict__ src,
                                                   const int* __restrict__ dst,
                                                   int* __restrict__ cnt_s,
                                                   int* __restrict__ cnt_d, int E) {
    int e = blockIdx.x * 256 + threadIdx.x;
    if (e < E) {
        atomicAdd(&cnt_s[src[e]], 1);
        atomicAdd(&cnt_d[dst[e]], 1);
    }
}

__global__ __launch_bounds__(1024) void scan_kernel(const int* __restrict__ cnt,
                                                    int* __restrict__ offs) {
    __shared__ int sums[1024];
    const int PER = (NN + 1023) / 1024;
    int tid = threadIdx.x;
    int base = tid * PER;
    int s = 0;
    for (int i = 0; i < PER; ++i) {
        int idx = base + i;
        if (idx < NN) s += cnt[idx];
    }
    sums[tid] = s;
    __syncthreads();
    for (int off = 1; off < 1024; off <<= 1) {
        int v = (tid >= off) ? sums[tid - off] : 0;
        __syncthreads();
        sums[tid] += v;
        __syncthreads();
    }
    int run = (tid > 0) ? sums[tid - 1] : 0;
    for (int i = 0; i < PER; ++i) {
        int idx = base + i;
        if (idx < NN) { offs[idx] = run; run += cnt[idx]; }
    }
    if (tid == 1023) offs[NN] = sums[1023];
}

__global__ __launch_bounds__(256) void rsqrt_kernel(const int* __restrict__ cnt_s,
                                                    const int* __restrict__ cnt_d,
                                                    float* __restrict__ deg_s,
                                                    float* __restrict__ deg_d, int n) {
    int i = blockIdx.x * 256 + threadIdx.x;
    if (i < n) {
        deg_s[i] = rsqrtf(fmaxf((float)cnt_s[i], 1.0f));
        deg_d[i] = rsqrtf(fmaxf((float)cnt_d[i], 1.0f));
    }
}

__global__ __launch_bounds__(256) void scatter_kernel(const int* __restrict__ src,
                                                      const int* __restrict__ dst,
                                                      const int* __restrict__ offs,
                                                      int* __restrict__ cursor,
                                                      int* __restrict__ ssrc, int E) {
    int e = blockIdx.x * 256 + threadIdx.x;
    if (e < E) {
        int d = dst[e];
        int pos = atomicAdd(&cursor[d], 1);
        ssrc[offs[d] + pos] = src[e];
    }
}

// ---------------- emb f32 -> fp16 rows padded to K1, fused out_s scale ----------------
__global__ __launch_bounds__(256) void embh_kernel(const float* __restrict__ emb,
                                                   const float* __restrict__ deg_s,
                                                   __half* __restrict__ embh) {
    int tid = blockIdx.x * 256 + threadIdx.x;           // one uint2 (4 halfs) per thread
    const int CPR = K1 / 4;                             // 80 chunks per padded row
    const int total = NN * CPR;
    if (tid >= total) return;
    int node = tid / CPR, c = tid - node * CPR;
    int f = 4 * c;
    __half h[4] = {__half(0.f), __half(0.f), __half(0.f), __half(0.f)};
    if (f < D0) {                                       // D0%4==0 -> full float4 valid
        float sc = deg_s[node];
        float4 v = *(const float4*)(emb + (size_t)node * D0 + f);
        h[0] = __float2half(v.x * sc); h[1] = __float2half(v.y * sc);
        h[2] = __float2half(v.z * sc); h[3] = __float2half(v.w * sc);
    }
    *(uint2*)(embh + (size_t)node * K1 + f) = *(uint2*)h;
}

// ---------------- weight transpose -> bf16 ----------------
__global__ __launch_bounds__(256) void w1t_kernel(const float* __restrict__ W,
                                                  unsigned short* __restrict__ T) {
    int tid = blockIdx.x * 256 + threadIdx.x;
    if (tid >= K2 * K1) return;               // [448][320]
    int n = tid / K1, k = tid - n * K1;
    float v = (n < N1 && k < D0) ? W[k * N1 + n] : 0.f;
    T[tid] = f2bf(v);
}

__global__ __launch_bounds__(256) void w2t_kernel(const float* __restrict__ W,
                                                  unsigned short* __restrict__ T) {
    int tid = blockIdx.x * 256 + threadIdx.x;
    if (tid >= N2 * K2) return;               // [512][448]
    int n = tid / K2, k = tid - n * K2;
    float v = (k < N1) ? W[k * N2 + n] : 0.f;
    T[tid] = f2bf(v);
}

// ---------------- CSR aggregation: uint4 gathers, unroll x8 ----------------
// O[n][:] = bf16( nscale[n] * sum_{s in Nin(n)} X[s][:] )
// X: fp16, LD halfs per row (LD%8==0), D8 = LD/8 uint4 chunks (lane l < D8 owns
// features 8l..8l+7). O: [NNP][KP] bf16 (KP/8 chunks; chunks >= D8 are zeros).
template <int LD, int KP>
__global__ __launch_bounds__(256) void agg_h_kernel(
    const __half* __restrict__ X, const int* __restrict__ offs,
    const int* __restrict__ ssrc, const float* __restrict__ nscale,
    unsigned short* __restrict__ O) {
    constexpr int D8 = LD / 8;        // gather chunks per row (40 / 50)
    constexpr int O8 = KP / 8;        // output chunks per row (40 / 56)
    int node = blockIdx.x * 4 + (threadIdx.x >> 6);
    if (node >= NNP) return;
    int l = threadIdx.x & 63;
    bool act = l < D8;
    const uint4* Xq = (const uint4*)X;

    float a[8] = {0.f, 0.f, 0.f, 0.f, 0.f, 0.f, 0.f, 0.f};

#define ACCUM(U) { const __half2* hp = (const __half2*)&(U);                        \
                   float2 f0 = __half22float2(hp[0]), f1 = __half22float2(hp[1]);   \
                   float2 f2 = __half22float2(hp[2]), f3 = __half22float2(hp[3]);   \
                   a[0] += f0.x; a[1] += f0.y; a[2] += f1.x; a[3] += f1.y;          \
                   a[4] += f2.x; a[5] += f2.y; a[6] += f3.x; a[7] += f3.y; }

    if (node < NN) {
        int j = offs[node], end = offs[node + 1];
        for (; j + 8 <= end; j += 8) {          // 8 independent 16B gathers in flight
            uint4 u0, u1, u2, u3, u4, u5, u6, u7;
            int s0 = ssrc[j + 0], s1 = ssrc[j + 1], s2 = ssrc[j + 2], s3 = ssrc[j + 3];
            int s4 = ssrc[j + 4], s5 = ssrc[j + 5], s6 = ssrc[j + 6], s7 = ssrc[j + 7];
            if (act) {
                u0 = Xq[(size_t)s0 * D8 + l]; u1 = Xq[(size_t)s1 * D8 + l];
                u2 = Xq[(size_t)s2 * D8 + l]; u3 = Xq[(size_t)s3 * D8 + l];
                u4 = Xq[(size_t)s4 * D8 + l]; u5 = Xq[(size_t)s5 * D8 + l];
                u6 = Xq[(size_t)s6 * D8 + l]; u7 = Xq[(size_t)s7 * D8 + l];
                ACCUM(u0); ACCUM(u1); ACCUM(u2); ACCUM(u3);
                ACCUM(u4); ACCUM(u5); ACCUM(u6); ACCUM(u7);
            }
        }
        for (; j + 2 <= end; j += 2) {
            int s0 = ssrc[j + 0], s1 = ssrc[j + 1];
            if (act) {
                uint4 u0 = Xq[(size_t)s0 * D8 + l];
                uint4 u1 = Xq[(size_t)s1 * D8 + l];
                ACCUM(u0); ACCUM(u1);
            }
        }
        for (; j < end; ++j) {
            int s0 = ssrc[j];
            if (act) { uint4 u0 = Xq[(size_t)s0 * D8 + l]; ACCUM(u0); }
        }
        float ns = nscale[node];
#pragma unroll
        for (int i = 0; i < 8; ++i) a[i] *= ns;
    }
#undef ACCUM

    if (l < O8) {
        unsigned short hv[8];
#pragma unroll
        for (int i = 0; i < 8; ++i) hv[i] = f2bf(a[i]);   // a==0 for lanes >= D8 / pad rows
        *(uint4*)(O + (size_t)node * KP + 8 * l) = *(uint4*)hv;
    }
}

// ---------------- pure-bf16 MFMA GEMM ----------------
// C[m][n] = epi( sum_k A[m][k] * BT[n][k] ), A [NNP][Kpad], BT [Npad][Kpad] bf16.
// Tile 128x64, BK=64, 4 waves (2x2), wave tile 64x32.
// WRITE_HALF: C is fp16 (h2 path, with lrelu*rs); else f32 plain.
template <bool LRELU_SCALE, bool WRITE_HALF>
__global__ __launch_bounds__(256) void gemm_bf16_kernel(
    const unsigned short* __restrict__ A, const unsigned short* __restrict__ BT,
    const float* __restrict__ bias, const float* __restrict__ rs,
    void* __restrict__ Cv, int nbn, int Kpad, int Nvalid, int Cld) {
    __shared__ unsigned short lds[12288];     // 24KB: A 8192 shorts | B 4096 shorts
    const int AOF = 0, BOF = 8192;

    // bijective XCD-chunked swizzle, n-fast decode for A-tile L2 reuse
    int nwg = (int)gridDim.x, orig = (int)blockIdx.x;
    int q8 = nwg >> 3, r8 = nwg & 7;
    int xc = orig & 7, o8 = orig >> 3;
    int wg = (xc < r8 ? xc * (q8 + 1) : r8 * (q8 + 1) + (xc - r8) * q8) + o8;
    int bn = wg % nbn, bm = wg / nbn;
    int m0 = bm * 128, n0 = bn * 64;

    int t = threadIdx.x, l = t & 63, w = t >> 6;
    int wm = w >> 1, wn = w & 1;

    f32x4 acc[4][2] = {};

    for (int k0 = 0; k0 < Kpad; k0 += 64) {
        // stage A tile (128 x 64): 4 x 16B chunks per thread; pre-swizzled global k-slot
#pragma unroll
        for (int j = 0; j < 4; ++j) {
            int c = j * 256 + t;
            int r = c >> 3, qs = c & 7;
            size_t goff = (size_t)(m0 + r) * Kpad + k0 + ((qs ^ (r & 7)) << 3);
            int lbase = (j * 256 + w * 64) * 8;
            __builtin_amdgcn_global_load_lds(
                (const __attribute__((address_space(1))) void*)(A + goff),
                (__attribute__((address_space(3))) void*)&lds[AOF + lbase], 16, 0, 0);
        }
        // stage B^T tile (64 x 64): 2 chunks per thread
#pragma unroll
        for (int j = 0; j < 2; ++j) {
            int c = j * 256 + t;
            int r = c >> 3, qs = c & 7;
            size_t goff = (size_t)(n0 + r) * Kpad + k0 + ((qs ^ (r & 7)) << 3);
            int lbase = (j * 256 + w * 64) * 8;
            __builtin_amdgcn_global_load_lds(
                (const __attribute__((address_space(1))) void*)(BT + goff),
                (__attribute__((address_space(3))) void*)&lds[BOF + lbase], 16, 0, 0);
        }
        __syncthreads();

#pragma unroll
        for (int ks = 0; ks < 2; ++ks) {
            bf16x8 bfr[2];
#pragma unroll
            for (int ni = 0; ni < 2; ++ni) {
                int n = wn * 32 + ni * 16 + (l & 15);
                int slot = ks * 4 + (l >> 4);
                int idx = n * 64 + ((slot ^ (n & 7)) << 3);
                bfr[ni] = *(const bf16x8*)&lds[BOF + idx];
            }
#pragma unroll
            for (int mi = 0; mi < 4; ++mi) {
                int m = wm * 64 + mi * 16 + (l & 15);
                int slot = ks * 4 + (l >> 4);
                int idx = m * 64 + ((slot ^ (m & 7)) << 3);
                bf16x8 afr = *(const bf16x8*)&lds[AOF + idx];
#pragma unroll
                for (int ni = 0; ni < 2; ++ni)
                    acc[mi][ni] = __builtin_amdgcn_mfma_f32_16x16x32_bf16(afr, bfr[ni], acc[mi][ni], 0, 0, 0);
            }
        }
        __syncthreads();
    }

    // epilogue: C/D layout col = lane&15, row = (lane>>4)*4 + reg
#pragma unroll
    for (int mi = 0; mi < 4; ++mi) {
        int mbase = m0 + wm * 64 + mi * 16 + ((l >> 4) << 2);
#pragma unroll
        for (int q = 0; q < 4; ++q) {
            int m = mbase + q;
            if (m >= NN) continue;
            float scale = LRELU_SCALE ? rs[m] : 1.0f;
#pragma unroll
            for (int ni = 0; ni < 2; ++ni) {
                int n = n0 + wn * 32 + ni * 16 + (l & 15);
                if (n >= Nvalid) continue;
                float v = acc[mi][ni][q] + bias[n];
                if (LRELU_SCALE) { v = v >= 0.f ? v : 0.2f * v; v *= scale; }
                if (WRITE_HALF)
                    ((__half*)Cv)[(size_t)m * Cld + n] = __float2half(v);
                else
                    ((float*)Cv)[(size_t)m * Cld + n] = v;
            }
        }
    }
}

extern "C" void kernel_launch(void* const* d_in, const int* in_sizes, int n_in,
                              void* d_out, int out_size, void* d_ws, size_t ws_size,
                              hipStream_t stream) {
    const float* emb = (const float*)d_in[0];
    const float* W1  = (const float*)d_in[1];
    const float* b1  = (const float*)d_in[2];
    const float* W2  = (const float*)d_in[3];
    const float* b2  = (const float*)d_in[4];
    const int*   src = (const int*)d_in[5];
    const int*   dst = (const int*)d_in[6];
    const int E = in_sizes[5];

    // ws layout (~78.8MB total):
    //   [0, 32.0MB)      A1 bf16 [NNP][320]
    //   [32.0, 76.9MB)   A2 bf16 [NNP][448]; embh fp16 [NN][320] (32MB) overlaps
    //                    A2's region but is dead before agg2 writes A2.
    //   [76.9MB, ...)    W1T bf16 [448][320], W2T bf16 [512][448]
    unsigned short* A1   = (unsigned short*)d_ws;
    unsigned short* A2   = A1 + (size_t)NNP * K1;
    __half*         embh = (__half*)A2;
    unsigned short* W1T  = A2 + (size_t)NNP * K2;
    unsigned short* W2T  = W1T + (size_t)K2 * K1;

    // d_out layout: h2 fp16 [NN][400] (40MB) | CSR + scales tail (4.4MB).
    // Everything here is dead before the final GEMM overwrites d_out.
    __half* h2  = (__half*)d_out;
    float*  out = (float*)d_out;
    char* tail = (char*)d_out + (size_t)NN * N1 * sizeof(__half);
    int* cnt_s  = (int*)tail;                // NN
    int* cnt_d  = cnt_s + NN;                // NN
    int* offs   = cnt_d + NN;                // NN+1
    int* cursor = offs + NN + 1;             // NN
    int* ssrc   = cursor + NN;               // E
    float* deg_s = (float*)(ssrc + E);       // NN (out_s)
    float* deg_d = deg_s + NN;               // NN (in_s)

    hipMemsetAsync(cnt_s, 0, (size_t)(4 * NN + 1) * sizeof(int), stream);

    hist_kernel<<<(E + 255) / 256, 256, 0, stream>>>(src, dst, cnt_s, cnt_d, E);
    scan_kernel<<<1, 1024, 0, stream>>>(cnt_d, offs);
    rsqrt_kernel<<<(NN + 255) / 256, 256, 0, stream>>>(cnt_s, cnt_d, deg_s, deg_d, NN);
    scatter_kernel<<<(E + 255) / 256, 256, 0, stream>>>(src, dst, offs, cursor, ssrc, E);

    // embh = fp16(emb * out_s), rows padded to 320 halfs (zeros)
    embh_kernel<<<(NN * (K1 / 4) + 255) / 256, 256, 0, stream>>>(emb, deg_s, embh);
    w1t_kernel<<<(K2 * K1 + 255) / 256, 256, 0, stream>>>(W1, W1T);
    w2t_kernel<<<(N2 * K2 + 255) / 256, 256, 0, stream>>>(W2, W2T);

    // layer 1: A1[n] = bf16( in_s[n] * sum embh[s] )   (LD=320, KP=320)
    agg_h_kernel<K1, K1><<<NNP / 4, 256, 0, stream>>>(embh, offs, ssrc, deg_d, A1);

    // h2 = fp16( lrelu(A1 @ W1 + b1) * out_s )
    gemm_bf16_kernel<true, true><<<391 * 7, 256, 0, stream>>>(
        A1, W1T, b1, deg_s, h2, 7, K1, N1, N1);

    // layer 2: A2[n] = bf16( in_s[n] * sum h2[s] )     (LD=400, KP=448)
    agg_h_kernel<N1, K2><<<NNP / 4, 256, 0, stream>>>(h2, offs, ssrc, deg_d, A2);

    // out = A2 @ W2 + b2   (f32)
    gemm_bf16_kernel<false, false><<<391 * 8, 256, 0, stream>>>(
        A2, W2T, b2, nullptr, out, 8, K2, N2, N2);
}

// Round 9
// 418.829 us; speedup vs baseline: 19.4708x; 1.1527x over previous
//
#include <hip/hip_runtime.h>
#include <hip/hip_fp16.h>

#define NN   50000      // nodes
#define NNP  50048      // padded to 128-multiple (391 * 128)
#define D0   300        // emb dim
#define K1   320        // D0 padded to 64-multiple (embh row stride too)
#define N1   400        // layer-1 out dim
#define K2   448        // N1 padded to 64-multiple (= GEMM2 K)
#define N2   512        // layer-2 out dim
#define NBLK 196        // scan blocks: 196*256 = 50176 >= NN

typedef __attribute__((ext_vector_type(8))) short bf16x8;
typedef __attribute__((ext_vector_type(4))) float f32x4;
typedef __attribute__((ext_vector_type(4))) unsigned int u32x4;   // clang vector (NT-store ok)

__device__ __forceinline__ unsigned short f2bf(float x) {   // rn-even f32->bf16
    union { float f; unsigned u; } v; v.f = x;
    unsigned r = v.u + 0x7fffu + ((v.u >> 16) & 1u);
    return (unsigned short)(r >> 16);
}

// ---------------- CSR build ----------------
__global__ __launch_bounds__(256) void hist_kernel(const int* __restrict__ src,
                                                   const int* __restrict__ dst,
                                                   int* __restrict__ cnt_s,
                                                   int* __restrict__ cnt_d, int E) {
    int e = blockIdx.x * 256 + threadIdx.x;
    if (e < E) {
        atomicAdd(&cnt_s[src[e]], 1);
        atomicAdd(&cnt_d[dst[e]], 1);
    }
}

// block-local exclusive scan of cnt_d; offs gets local exclusive, bsum gets block total
__global__ __launch_bounds__(256) void scan_blk_kernel(const int* __restrict__ cnt,
                                                       int* __restrict__ offs,
                                                       int* __restrict__ bsum) {
    __shared__ int sh[256];
    int t = threadIdx.x, g = blockIdx.x * 256 + t;
    int v = (g < NN) ? cnt[g] : 0;
    sh[t] = v;
    __syncthreads();
    for (int off = 1; off < 256; off <<= 1) {
        int u = (t >= off) ? sh[t - off] : 0;
        __syncthreads();
        sh[t] += u;
        __syncthreads();
    }
    if (g < NN) offs[g] = sh[t] - v;
    if (t == 255) bsum[blockIdx.x] = sh[255];
}

// scan the 196 block sums -> exclusive block offsets
__global__ __launch_bounds__(256) void scan_top_kernel(const int* __restrict__ bsum,
                                                       int* __restrict__ boff) {
    __shared__ int sh[256];
    int t = threadIdx.x;
    int v = (t < NBLK) ? bsum[t] : 0;
    sh[t] = v;
    __syncthreads();
    for (int off = 1; off < 256; off <<= 1) {
        int u = (t >= off) ? sh[t - off] : 0;
        __syncthreads();
        sh[t] += u;
        __syncthreads();
    }
    if (t < NBLK) boff[t] = sh[t] - v;
}

// add block offsets; also compute rsqrt degree scales and offs[NN]=E
__global__ __launch_bounds__(256) void scan_fix_kernel(int* __restrict__ offs,
                                                       const int* __restrict__ boff,
                                                       const int* __restrict__ cnt_s,
                                                       const int* __restrict__ cnt_d,
                                                       float* __restrict__ deg_s,
                                                       float* __restrict__ deg_d, int E) {
    int g = blockIdx.x * 256 + threadIdx.x;
    if (g < NN) {
        offs[g] += boff[blockIdx.x];
        deg_s[g] = rsqrtf(fmaxf((float)cnt_s[g], 1.0f));
        deg_d[g] = rsqrtf(fmaxf((float)cnt_d[g], 1.0f));
    }
    if (g == NN) offs[NN] = E;
}

__global__ __launch_bounds__(256) void scatter_kernel(const int* __restrict__ src,
                                                      const int* __restrict__ dst,
                                                      const int* __restrict__ offs,
                                                      int* __restrict__ cursor,
                                                      int* __restrict__ ssrc, int E) {
    int e = blockIdx.x * 256 + threadIdx.x;
    if (e < E) {
        int d = dst[e];
        int pos = atomicAdd(&cursor[d], 1);
        ssrc[offs[d] + pos] = src[e];
    }
}

// ---------------- emb f32 -> fp16 rows padded to K1, fused out_s scale ----------------
__global__ __launch_bounds__(256) void embh_kernel(const float* __restrict__ emb,
                                                   const float* __restrict__ deg_s,
                                                   __half* __restrict__ embh) {
    int tid = blockIdx.x * 256 + threadIdx.x;           // one uint2 (4 halfs) per thread
    const int CPR = K1 / 4;                             // 80 chunks per padded row
    const int total = NN * CPR;
    if (tid >= total) return;
    int node = tid / CPR, c = tid - node * CPR;
    int f = 4 * c;
    __half h[4] = {__half(0.f), __half(0.f), __half(0.f), __half(0.f)};
    if (f < D0) {                                       // D0%4==0 -> full float4 valid
        float sc = deg_s[node];
        float4 v = *(const float4*)(emb + (size_t)node * D0 + f);
        h[0] = __float2half(v.x * sc); h[1] = __float2half(v.y * sc);
        h[2] = __float2half(v.z * sc); h[3] = __float2half(v.w * sc);
    }
    *(uint2*)(embh + (size_t)node * K1 + f) = *(uint2*)h;
}

// ---------------- both weight transposes -> bf16 in one dispatch ----------------
__global__ __launch_bounds__(256) void wt_kernel(const float* __restrict__ W1,
                                                 const float* __restrict__ W2,
                                                 unsigned short* __restrict__ T1,
                                                 unsigned short* __restrict__ T2) {
    int tid = blockIdx.x * 256 + threadIdx.x;
    if (tid < K2 * K1) {                      // W1T [448][320]
        int n = tid / K1, k = tid - n * K1;
        float v = (n < N1 && k < D0) ? W1[k * N1 + n] : 0.f;
        T1[tid] = f2bf(v);
    } else {
        int u = tid - K2 * K1;
        if (u >= N2 * K2) return;             // W2T [512][448]
        int n = u / K2, k = u - n * K2;
        float v = (k < N1) ? W2[k * N2 + n] : 0.f;
        T2[u] = f2bf(v);
    }
}

// ---------------- CSR aggregation: uint4 gathers, unroll x8, NT output stores ----------------
// O[n][:] = bf16( nscale[n] * sum_{s in Nin(n)} X[s][:] )
template <int LD, int KP>
__global__ __launch_bounds__(256) void agg_h_kernel(
    const __half* __restrict__ X, const int* __restrict__ offs,
    const int* __restrict__ ssrc, const float* __restrict__ nscale,
    unsigned short* __restrict__ O) {
    constexpr int D8 = LD / 8;        // gather chunks per row (40 / 50)
    constexpr int O8 = KP / 8;        // output chunks per row (40 / 56)
    int node = blockIdx.x * 4 + (threadIdx.x >> 6);
    if (node >= NNP) return;
    int l = threadIdx.x & 63;
    bool act = l < D8;
    const uint4* Xq = (const uint4*)X;

    float a[8] = {0.f, 0.f, 0.f, 0.f, 0.f, 0.f, 0.f, 0.f};

#define ACCUM(U) { const __half2* hp = (const __half2*)&(U);                        \
                   float2 f0 = __half22float2(hp[0]), f1 = __half22float2(hp[1]);   \
                   float2 f2 = __half22float2(hp[2]), f3 = __half22float2(hp[3]);   \
                   a[0] += f0.x; a[1] += f0.y; a[2] += f1.x; a[3] += f1.y;          \
                   a[4] += f2.x; a[5] += f2.y; a[6] += f3.x; a[7] += f3.y; }

    if (node < NN) {
        int j = offs[node], end = offs[node + 1];
        for (; j + 8 <= end; j += 8) {          // 8 independent 16B gathers in flight
            uint4 u0, u1, u2, u3, u4, u5, u6, u7;
            int s0 = ssrc[j + 0], s1 = ssrc[j + 1], s2 = ssrc[j + 2], s3 = ssrc[j + 3];
            int s4 = ssrc[j + 4], s5 = ssrc[j + 5], s6 = ssrc[j + 6], s7 = ssrc[j + 7];
            if (act) {
                u0 = Xq[(size_t)s0 * D8 + l]; u1 = Xq[(size_t)s1 * D8 + l];
                u2 = Xq[(size_t)s2 * D8 + l]; u3 = Xq[(size_t)s3 * D8 + l];
                u4 = Xq[(size_t)s4 * D8 + l]; u5 = Xq[(size_t)s5 * D8 + l];
                u6 = Xq[(size_t)s6 * D8 + l]; u7 = Xq[(size_t)s7 * D8 + l];
                ACCUM(u0); ACCUM(u1); ACCUM(u2); ACCUM(u3);
                ACCUM(u4); ACCUM(u5); ACCUM(u6); ACCUM(u7);
            }
        }
        for (; j + 2 <= end; j += 2) {
            int s0 = ssrc[j + 0], s1 = ssrc[j + 1];
            if (act) {
                uint4 u0 = Xq[(size_t)s0 * D8 + l];
                uint4 u1 = Xq[(size_t)s1 * D8 + l];
                ACCUM(u0); ACCUM(u1);
            }
        }
        for (; j < end; ++j) {
            int s0 = ssrc[j];
            if (act) { uint4 u0 = Xq[(size_t)s0 * D8 + l]; ACCUM(u0); }
        }
        float ns = nscale[node];
#pragma unroll
        for (int i = 0; i < 8; ++i) a[i] *= ns;
    }
#undef ACCUM

    if (l < O8) {
        unsigned short hv[8];
#pragma unroll
        for (int i = 0; i < 8; ++i) hv[i] = f2bf(a[i]);   // a==0 for lanes >= D8 / pad rows
        // nontemporal: don't let the 32-45MB output stream evict the gather set from L2
        __builtin_nontemporal_store(*(u32x4*)hv, (u32x4*)(O + (size_t)node * KP + 8 * l));
    }
}

// ---------------- pure-bf16 MFMA GEMM ----------------
// C[m][n] = epi( sum_k A[m][k] * BT[n][k] ), A [NNP][Kpad], BT [Npad][Kpad] bf16.
// Tile 128x64, BK=64, 4 waves (2x2), wave tile 64x32.
template <bool LRELU_SCALE, bool WRITE_HALF>
__global__ __launch_bounds__(256) void gemm_bf16_kernel(
    const unsigned short* __restrict__ A, const unsigned short* __restrict__ BT,
    const float* __restrict__ bias, const float* __restrict__ rs,
    void* __restrict__ Cv, int nbn, int Kpad, int Nvalid, int Cld) {
    __shared__ unsigned short lds[12288];     // 24KB: A 8192 shorts | B 4096 shorts
    const int AOF = 0, BOF = 8192;

    // bijective XCD-chunked swizzle, n-fast decode for A-tile L2 reuse
    int nwg = (int)gridDim.x, orig = (int)blockIdx.x;
    int q8 = nwg >> 3, r8 = nwg & 7;
    int xc = orig & 7, o8 = orig >> 3;
    int wg = (xc < r8 ? xc * (q8 + 1) : r8 * (q8 + 1) + (xc - r8) * q8) + o8;
    int bn = wg % nbn, bm = wg / nbn;
    int m0 = bm * 128, n0 = bn * 64;

    int t = threadIdx.x, l = t & 63, w = t >> 6;
    int wm = w >> 1, wn = w & 1;

    f32x4 acc[4][2] = {};

    for (int k0 = 0; k0 < Kpad; k0 += 64) {
#pragma unroll
        for (int j = 0; j < 4; ++j) {
            int c = j * 256 + t;
            int r = c >> 3, qs = c & 7;
            size_t goff = (size_t)(m0 + r) * Kpad + k0 + ((qs ^ (r & 7)) << 3);
            int lbase = (j * 256 + w * 64) * 8;
            __builtin_amdgcn_global_load_lds(
                (const __attribute__((address_space(1))) void*)(A + goff),
                (__attribute__((address_space(3))) void*)&lds[AOF + lbase], 16, 0, 0);
        }
#pragma unroll
        for (int j = 0; j < 2; ++j) {
            int c = j * 256 + t;
            int r = c >> 3, qs = c & 7;
            size_t goff = (size_t)(n0 + r) * Kpad + k0 + ((qs ^ (r & 7)) << 3);
            int lbase = (j * 256 + w * 64) * 8;
            __builtin_amdgcn_global_load_lds(
                (const __attribute__((address_space(1))) void*)(BT + goff),
                (__attribute__((address_space(3))) void*)&lds[BOF + lbase], 16, 0, 0);
        }
        __syncthreads();

#pragma unroll
        for (int ks = 0; ks < 2; ++ks) {
            bf16x8 bfr[2];
#pragma unroll
            for (int ni = 0; ni < 2; ++ni) {
                int n = wn * 32 + ni * 16 + (l & 15);
                int slot = ks * 4 + (l >> 4);
                int idx = n * 64 + ((slot ^ (n & 7)) << 3);
                bfr[ni] = *(const bf16x8*)&lds[BOF + idx];
            }
#pragma unroll
            for (int mi = 0; mi < 4; ++mi) {
                int m = wm * 64 + mi * 16 + (l & 15);
                int slot = ks * 4 + (l >> 4);
                int idx = m * 64 + ((slot ^ (m & 7)) << 3);
                bf16x8 afr = *(const bf16x8*)&lds[AOF + idx];
#pragma unroll
                for (int ni = 0; ni < 2; ++ni)
                    acc[mi][ni] = __builtin_amdgcn_mfma_f32_16x16x32_bf16(afr, bfr[ni], acc[mi][ni], 0, 0, 0);
            }
        }
        __syncthreads();
    }

    // epilogue: C/D layout col = lane&15, row = (lane>>4)*4 + reg
#pragma unroll
    for (int mi = 0; mi < 4; ++mi) {
        int mbase = m0 + wm * 64 + mi * 16 + ((l >> 4) << 2);
#pragma unroll
        for (int q = 0; q < 4; ++q) {
            int m = mbase + q;
            if (m >= NN) continue;
            float scale = LRELU_SCALE ? rs[m] : 1.0f;
#pragma unroll
            for (int ni = 0; ni < 2; ++ni) {
                int n = n0 + wn * 32 + ni * 16 + (l & 15);
                if (n >= Nvalid) continue;
                float v = acc[mi][ni][q] + bias[n];
                if (LRELU_SCALE) { v = v >= 0.f ? v : 0.2f * v; v *= scale; }
                if (WRITE_HALF)
                    ((__half*)Cv)[(size_t)m * Cld + n] = __float2half(v);
                else
                    ((float*)Cv)[(size_t)m * Cld + n] = v;
            }
        }
    }
}

extern "C" void kernel_launch(void* const* d_in, const int* in_sizes, int n_in,
                              void* d_out, int out_size, void* d_ws, size_t ws_size,
                              hipStream_t stream) {
    const float* emb = (const float*)d_in[0];
    const float* W1  = (const float*)d_in[1];
    const float* b1  = (const float*)d_in[2];
    const float* W2  = (const float*)d_in[3];
    const float* b2  = (const float*)d_in[4];
    const int*   src = (const int*)d_in[5];
    const int*   dst = (const int*)d_in[6];
    const int E = in_sizes[5];

    // ws layout (~78.8MB total):
    //   [0, 32.0MB)      A1 bf16 [NNP][320]
    //   [32.0, 76.9MB)   A2 bf16 [NNP][448]; embh fp16 [NN][320] (32MB) overlaps
    //                    A2's region but is dead before agg2 writes A2.
    //   [76.9MB, ...)    W1T bf16 [448][320], W2T bf16 [512][448]
    unsigned short* A1   = (unsigned short*)d_ws;
    unsigned short* A2   = A1 + (size_t)NNP * K1;
    __half*         embh = (__half*)A2;
    unsigned short* W1T  = A2 + (size_t)NNP * K2;
    unsigned short* W2T  = W1T + (size_t)K2 * K1;

    // d_out layout: h2 fp16 [NN][400] (40MB) | CSR + scales tail.
    // Everything here is dead before the final GEMM overwrites d_out.
    __half* h2  = (__half*)d_out;
    float*  out = (float*)d_out;
    char* tail = (char*)d_out + (size_t)NN * N1 * sizeof(__half);
    int* cnt_s  = (int*)tail;                // NN
    int* cnt_d  = cnt_s + NN;                // NN
    int* cursor = cnt_d + NN;                // NN   (memset covers these 3*NN)
    int* offs   = cursor + NN;               // NN+1
    int* bsum   = offs + NN + 1;             // NBLK
    int* boff   = bsum + NBLK;               // NBLK
    int* ssrc   = boff + NBLK;               // E
    float* deg_s = (float*)(ssrc + E);       // NN (out_s)
    float* deg_d = deg_s + NN;               // NN (in_s)
    // tail total ~4.6MB << 22.4MB

    hipMemsetAsync(cnt_s, 0, (size_t)(3 * NN) * sizeof(int), stream);

    hist_kernel<<<(E + 255) / 256, 256, 0, stream>>>(src, dst, cnt_s, cnt_d, E);
    scan_blk_kernel<<<NBLK, 256, 0, stream>>>(cnt_d, offs, bsum);
    scan_top_kernel<<<1, 256, 0, stream>>>(bsum, boff);
    scan_fix_kernel<<<NBLK, 256, 0, stream>>>(offs, boff, cnt_s, cnt_d, deg_s, deg_d, E);
    scatter_kernel<<<(E + 255) / 256, 256, 0, stream>>>(src, dst, offs, cursor, ssrc, E);

    // embh = fp16(emb * out_s), rows padded to 320 halfs (zeros)
    embh_kernel<<<(NN * (K1 / 4) + 255) / 256, 256, 0, stream>>>(emb, deg_s, embh);
    wt_kernel<<<(K2 * K1 + N2 * K2 + 255) / 256, 256, 0, stream>>>(W1, W2, W1T, W2T);

    // layer 1: A1[n] = bf16( in_s[n] * sum embh[s] )   (LD=320, KP=320)
    agg_h_kernel<K1, K1><<<NNP / 4, 256, 0, stream>>>(embh, offs, ssrc, deg_d, A1);

    // h2 = fp16( lrelu(A1 @ W1 + b1) * out_s )
    gemm_bf16_kernel<true, true><<<391 * 7, 256, 0, stream>>>(
        A1, W1T, b1, deg_s, h2, 7, K1, N1, N1);

    // layer 2: A2[n] = bf16( in_s[n] * sum h2[s] )     (LD=400, KP=448)
    agg_h_kernel<N1, K2><<<NNP / 4, 256, 0, stream>>>(h2, offs, ssrc, deg_d, A2);

    // out = A2 @ W2 + b2   (f32)
    gemm_bf16_kernel<false, false><<<391 * 8, 256, 0, stream>>>(
        A2, W2T, b2, nullptr, out, 8, K2, N2, N2);
}